// Round 4
// baseline (580.611 us; speedup 1.0000x reference)
//
#include <hip/hip_runtime.h>
#include <math.h>
#include <float.h>

// Problem constants (HierNet_55705725829422)
#define NN 50000      // nodes
#define EE 800000     // edges
#define CAP 64        // max in-degree capacity (Poisson(16): P(>=64) ~ 1e-19)

typedef unsigned short ushort_t;
typedef short short8 __attribute__((ext_vector_type(8)));
typedef float floatx4 __attribute__((ext_vector_type(4)));

__device__ __constant__ float kAVG_LOG = 2.8332133440562162f; // log(17)

__device__ inline ushort_t f2bf(float v) {
    union { float f; unsigned u; } x; x.f = v;
    unsigned r = x.u + 0x7fffu + ((x.u >> 16) & 1u);
    return (ushort_t)(r >> 16);
}
__device__ inline float bf2f(ushort_t b) {
    union { unsigned u; float f; } x; x.u = ((unsigned)b) << 16; return x.f;
}
__device__ inline void splitbf(float v, ushort_t& hi, ushort_t& lo) {
    hi = f2bf(v);
    lo = f2bf(v - bf2f(hi));
}

__global__ __launch_bounds__(256) void zero_init(int* cnt, float* pool) {
    int i = blockIdx.x * 256 + threadIdx.x;
    if (i < NN) cnt[i] = 0;
    if (i < 64 * 64) pool[i] = 0.f;
}

__global__ __launch_bounds__(256) void build_csr(const int* __restrict__ ei, const float* __restrict__ ea,
                                                 int* __restrict__ cnt, int* __restrict__ csr_src,
                                                 float2* __restrict__ csr_ea) {
    int e = blockIdx.x * 256 + threadIdx.x;
    if (e >= EE) return;
    int s = ei[e];
    int d = ei[EE + e];
    float2 v = *(const float2*)(ea + 2 * e);
    int p = atomicAdd(&cnt[d], 1);
    if (p < CAP) {
        csr_src[d * CAP + p] = s;
        csr_ea[d * CAP + p] = v;
    }
}

__global__ __launch_bounds__(256) void split_x(const float* __restrict__ x, ushort_t* __restrict__ hi,
                                               ushort_t* __restrict__ lo, int n) {
    int i = blockIdx.x * 256 + threadIdx.x;
    if (i < n) splitbf(x[i], hi[i], lo[i]);
}

// per-layer A/B-projection weight prep: U, Wab (fp32, for fp32 gemm_bias), bias_ab
template <int F>
__global__ __launch_bounds__(256) void prep_ab(const float* __restrict__ We, const float* __restrict__ be,
                                               const float* __restrict__ Wpre, const float* __restrict__ bpre,
                                               float* __restrict__ U, float* __restrict__ Wab,
                                               float* __restrict__ bias_ab) {
    const int TF = 2 * F;
    int tid = threadIdx.x;
    for (int idx = tid; idx < 2 * TF; idx += 256) {
        int c = idx / TF, f = idx % TF;
        int t = f / F, o = f % F;
        float s = 0.f;
        for (int g = 0; g < F; ++g)
            s += We[c * F + g] * Wpre[((size_t)t * 3 * F + 2 * F + g) * F + o];
        U[idx] = s;
    }
    for (int idx = tid; idx < F * 2 * TF; idx += 256) {
        int g = idx / (2 * TF), cc = idx % (2 * TF);
        int t, o, row;
        if (cc < TF) { t = cc / F; o = cc % F; row = g; }
        else { int c2 = cc - TF; t = c2 / F; o = c2 % F; row = F + g; }
        Wab[idx] = Wpre[((size_t)t * 3 * F + row) * F + o];
    }
    for (int cc = tid; cc < 2 * TF; cc += 256) {
        float v = 0.f;
        if (cc < TF) {
            int t = cc / F, o = cc % F;
            float s = 0.f;
            for (int g = 0; g < F; ++g)
                s += be[g] * Wpre[((size_t)t * 3 * F + 2 * F + g) * F + o];
            v = s + bpre[t * F + o];
        }
        bias_ab[cc] = v;
    }
}

// Folded Z/final weights, split to bf16 hi/lo, stored COL-MAJOR [192 cols][KT]
// col j_global = b*64 + j. Rows: k<F -> (b==0 ? Wfold : 0); k>=F -> Wz_b rows (t*4F+rr).
template <int F>
__global__ __launch_bounds__(256) void prep_zf(const float* __restrict__ Wpost, const float* __restrict__ Wlin,
                                               const float* __restrict__ bpost, const float* __restrict__ blin,
                                               ushort_t* __restrict__ Bh, ushort_t* __restrict__ Bl,
                                               float* __restrict__ bias_zf) {
    const int KT = 9 * F;
    int bx = blockIdx.x;  // 12 blocks x 16 cols
    int tid = threadIdx.x;
    for (int idx = tid; idx < 16 * KT; idx += 256) {
        int jj = idx / KT, k = idx % KT;
        int jg = bx * 16 + jj;
        int b = jg >> 6, j = jg & 63;
        float v = 0.f;
        if (k < F) {
            if (b == 0) {
                float s = 0.f;
                for (int t = 0; t < 2; ++t)
                    for (int c = 0; c < 32; ++c)
                        s += Wpost[((size_t)t * 13 * F + k) * 32 + c] * Wlin[(t * 32 + c) * 64 + j];
                v = s;
            }
        } else {
            int r = k - F;
            int t = r / (4 * F), rr = r - t * 4 * F;
            float s = 0.f;
            for (int c = 0; c < 32; ++c)
                s += Wpost[((size_t)t * 13 * F + F + b * 4 * F + rr) * 32 + c] * Wlin[(t * 32 + c) * 64 + j];
            v = s;
        }
        ushort_t h_, l_;
        splitbf(v, h_, l_);
        Bh[(size_t)jg * KT + k] = h_;
        Bl[(size_t)jg * KT + k] = l_;
    }
    if (bx == 0) {
        for (int j = tid; j < 64; j += 256) {
            float s = blin[j];
            for (int t = 0; t < 2; ++t)
                for (int c = 0; c < 32; ++c)
                    s += bpost[t * 32 + c] * Wlin[(t * 32 + c) * 64 + j];
            bias_zf[j] = s;
        }
    }
}

// fp32 GEMM for A/B projection: C[MxN] = A[MxK]@B[KxN] + bias. Tile 128x64, micro 8x4.
__global__ __launch_bounds__(256) void gemm_bias(const float* __restrict__ A, const float* __restrict__ B,
                                                 const float* __restrict__ bias, float* __restrict__ C,
                                                 int M, int K, int Ncols) {
    __shared__ float As[32][132];
    __shared__ float Bs[32][68];
    int m0 = blockIdx.x * 128, c0 = blockIdx.y * 64;
    int tid = threadIdx.x;
    int tx = tid & 15, ty = tid >> 4;
    int ms = tid >> 3, u = tid & 7;
    float acc[8][4] = {};
    for (int k0 = 0; k0 < K; k0 += 32) {
#pragma unroll
        for (int p = 0; p < 4; ++p) {
            int m = ms + 32 * p;
            int gm = m0 + m;
            float4 v = make_float4(0.f, 0.f, 0.f, 0.f);
            if (gm < M) v = *(const float4*)(A + (size_t)gm * K + k0 + u * 4);
            As[u * 4 + 0][m] = v.x; As[u * 4 + 1][m] = v.y;
            As[u * 4 + 2][m] = v.z; As[u * 4 + 3][m] = v.w;
        }
#pragma unroll
        for (int p = 0; p < 2; ++p) {
            int idx = tid + 256 * p;
            int kk = idx >> 4, q = idx & 15;
            *(float4*)&Bs[kk][q * 4] = *(const float4*)(B + (size_t)(k0 + kk) * Ncols + c0 + q * 4);
        }
        __syncthreads();
#pragma unroll 8
        for (int k = 0; k < 32; ++k) {
            float a0[8], b0[4];
            *(float4*)&a0[0] = *(const float4*)&As[k][ty * 8];
            *(float4*)&a0[4] = *(const float4*)&As[k][ty * 8 + 4];
            *(float4*)&b0[0] = *(const float4*)&Bs[k][tx * 4];
#pragma unroll
            for (int i = 0; i < 8; ++i)
#pragma unroll
                for (int j = 0; j < 4; ++j) acc[i][j] = fmaf(a0[i], b0[j], acc[i][j]);
        }
        __syncthreads();
    }
    float bj[4];
#pragma unroll
    for (int j = 0; j < 4; ++j) bj[j] = bias[c0 + tx * 4 + j];
#pragma unroll
    for (int i = 0; i < 8; ++i) {
        int gm = m0 + ty * 8 + i;
        if (gm >= M) continue;
        float4 v = make_float4(acc[i][0] + bj[0], acc[i][1] + bj[1], acc[i][2] + bj[2], acc[i][3] + bj[3]);
        *(float4*)(C + (size_t)gm * Ncols + c0 + tx * 4) = v;
    }
}

// aggregate: one wave per (node, 64-feature half). Emits agg as bf16 hi/lo splits.
template <int F>
__global__ __launch_bounds__(256) void aggregate(const float* __restrict__ AB, const int* __restrict__ cnt,
                                                 const int* __restrict__ csr_src, const float2* __restrict__ csr_ea,
                                                 const float* __restrict__ U, ushort_t* __restrict__ agg_hi,
                                                 ushort_t* __restrict__ agg_lo, float2* __restrict__ sc) {
    const int TF = 2 * F;
    const int SPN = TF / 64;
    int lane = threadIdx.x & 63;
    int slot = blockIdx.x * 4 + (threadIdx.x >> 6);
    int n = slot / SPN;
    int half = slot - n * SPN;
    if (n >= NN) return;
    int f = half * 64 + lane;

    float base = AB[(size_t)n * (2 * TF) + f];
    float u0 = U[f], u1 = U[TF + f];
    int deg = cnt[n];
    int ec = deg < CAP ? deg : CAP;

    float sum = 0.f, sq = 0.f, mn = FLT_MAX, mx = -FLT_MAX;
    if (ec > 0) {
        int ebase = n * CAP;
        int myi = lane < ec ? lane : ec - 1;
        int msrc = csr_src[ebase + myi];
        float2 mea = csr_ea[ebase + myi];
        const float* Bcol = AB + TF + f;
        for (int e = 0; e < ec; e += 8) {
            int sb[8]; float ex[8], ey[8], v[8];
#pragma unroll
            for (int i = 0; i < 8; ++i) {
                sb[i] = __shfl(msrc, e + i);
                ex[i] = __shfl(mea.x, e + i);
                ey[i] = __shfl(mea.y, e + i);
            }
#pragma unroll
            for (int i = 0; i < 8; ++i)
                if (e + i < ec) v[i] = Bcol[(size_t)sb[i] * (2 * TF)];
#pragma unroll
            for (int i = 0; i < 8; ++i) {
                if (e + i < ec) {
                    float q = fmaf(ex[i], u0, fmaf(ey[i], u1, v[i]));
                    sum += q;
                    sq = fmaf(q, q, sq);
                    mn = fminf(mn, q);
                    mx = fmaxf(mx, q);
                }
            }
        }
    }
    float d = (float)(deg > 1 ? deg : 1);
    float inv_d = 1.f / d;
    float mean_q = sum * inv_d;
    float var = sq * inv_d - mean_q * mean_q;
    float stdv = sqrtf(fmaxf(var, 0.f) + 1e-5f);
    bool has = deg > 0;
    float mean = has ? base + mean_q : 0.f;
    float vmn = has ? base + mn : 0.f;
    float vmx = has ? base + mx : 0.f;
    int t = f / F, o = f - t * F;
    size_t rowb = (size_t)n * (4 * TF) + (size_t)t * (4 * F);
    ushort_t h_, l_;
    splitbf(mean, h_, l_); agg_hi[rowb + o] = h_;         agg_lo[rowb + o] = l_;
    splitbf(vmn,  h_, l_); agg_hi[rowb + F + o] = h_;     agg_lo[rowb + F + o] = l_;
    splitbf(vmx,  h_, l_); agg_hi[rowb + 2 * F + o] = h_; agg_lo[rowb + 2 * F + o] = l_;
    splitbf(stdv, h_, l_); agg_hi[rowb + 3 * F + o] = h_; agg_lo[rowb + 3 * F + o] = l_;
    if (half == 0 && lane == 0) {
        float logd = logf(d + 1.f);
        sc[n] = make_float2(logd / kAVG_LOG, kAVG_LOG / logd);
    }
}

// MFMA split-bf16 merged Z+final GEMM.
// A' = [x | agg] [N x 9F] (hi/lo splits). B [9F x 192] col-major hi/lo.
// Y = Ah@Bh + Ah@Bl + Al@Bh. Epilogue: h = relu(Y0 + s1*Y1 + s2*Y2 + bias_zf).
// Block tile 128x192; 4 waves, each 32 rows x 192 cols (2x12 16x16x32 frags).
template <int F, bool POOL>
__global__ __launch_bounds__(256) void gemm_zf(
    const ushort_t* __restrict__ xs_hi, const ushort_t* __restrict__ xs_lo,
    const ushort_t* __restrict__ agg_hi, const ushort_t* __restrict__ agg_lo,
    const ushort_t* __restrict__ Bh, const ushort_t* __restrict__ Bl,
    const float* __restrict__ bias_zf, const float2* __restrict__ sc,
    float* __restrict__ H, ushort_t* __restrict__ H_hi, ushort_t* __restrict__ H_lo,
    const int* __restrict__ batch, float* __restrict__ pool) {
    const int KT = 9 * F;
    extern __shared__ char smem[];
    ushort_t* As = (ushort_t*)smem;          // [128][40]
    ushort_t* Bs = As + 128 * 40;            // [192][40]
    float* hbuf = (float*)smem;              // POOL alias [128][68]

    int m0 = blockIdx.x * 128;
    int tid = threadIdx.x;
    int lane = tid & 63;
    int wave = tid >> 6;
    int ln = lane & 15, quad = lane >> 4;
    int wrow = wave * 32;

    floatx4 acc0[12], acc1[12];
#pragma unroll
    for (int i = 0; i < 12; ++i) { acc0[i] = (floatx4)(0.f); acc1[i] = (floatx4)(0.f); }

    for (int seg = 0; seg < 3; ++seg) {
        const ushort_t* Axs = (seg < 2) ? xs_hi : xs_lo;
        const ushort_t* Ags = (seg < 2) ? agg_hi : agg_lo;
        const ushort_t* Bss = (seg == 1) ? Bl : Bh;
        for (int k0 = 0; k0 < KT; k0 += 32) {
            // stage A: 128 rows x 32k bf16 (512 16B chunks)
#pragma unroll
            for (int p = 0; p < 2; ++p) {
                int idx = tid + 256 * p;
                int row = idx >> 2, sg = idx & 3;
                int c0 = k0 + sg * 8;
                int gm = m0 + row;
                short8 v = {0, 0, 0, 0, 0, 0, 0, 0};
                if (gm < NN) {
                    const ushort_t* src = (c0 < F) ? (Axs + (size_t)gm * F + c0)
                                                   : (Ags + (size_t)gm * 8 * F + (c0 - F));
                    v = *(const short8*)src;
                }
                *(short8*)&As[row * 40 + sg * 8] = v;
            }
            // stage B: 192 cols x 32k (768 chunks), col-major source
#pragma unroll
            for (int p = 0; p < 3; ++p) {
                int idx = tid + 256 * p;
                int col = idx >> 2, sg = idx & 3;
                *(short8*)&Bs[col * 40 + sg * 8] =
                    *(const short8*)(Bss + (size_t)col * KT + k0 + sg * 8);
            }
            __syncthreads();
            short8 a0 = *(short8*)&As[(wrow + ln) * 40 + quad * 8];
            short8 a1 = *(short8*)&As[(wrow + 16 + ln) * 40 + quad * 8];
#pragma unroll
            for (int nt = 0; nt < 12; ++nt) {
                short8 b = *(short8*)&Bs[(nt * 16 + ln) * 40 + quad * 8];
                acc0[nt] = __builtin_amdgcn_mfma_f32_16x16x32_bf16(a0, b, acc0[nt], 0, 0, 0);
                acc1[nt] = __builtin_amdgcn_mfma_f32_16x16x32_bf16(a1, b, acc1[nt], 0, 0, 0);
            }
            __syncthreads();
        }
    }

    float bj[4];
#pragma unroll
    for (int j = 0; j < 4; ++j) bj[j] = bias_zf[j * 16 + ln];

#pragma unroll
    for (int mt = 0; mt < 2; ++mt) {
        floatx4* A = mt ? acc1 : acc0;
#pragma unroll
        for (int reg = 0; reg < 4; ++reg) {
            int r = wrow + mt * 16 + quad * 4 + reg;
            int gm = m0 + r;
            float2 s = make_float2(0.f, 0.f);
            if (gm < NN) s = sc[gm];
#pragma unroll
            for (int j = 0; j < 4; ++j) {
                float y = A[j][reg] + s.x * A[j + 4][reg] + s.y * A[j + 8][reg] + bj[j];
                y = fmaxf(y, 0.f);
                int col = j * 16 + ln;
                if (POOL) {
                    hbuf[r * 68 + col] = (gm < NN) ? y : 0.f;
                } else if (gm < NN) {
                    H[(size_t)gm * 64 + col] = y;
                    ushort_t h_, l_;
                    splitbf(y, h_, l_);
                    H_hi[(size_t)gm * 64 + col] = h_;
                    H_lo[(size_t)gm * 64 + col] = l_;
                }
            }
        }
    }
    if (POOL) {
        __syncthreads();
        int col = tid & 63, grp = tid >> 6;
        float acc = 0.f;
        int cur = -1;
        for (int i = 0; i < 32; ++i) {
            int r = grp * 32 + i;
            int gm = m0 + r;
            if (gm >= NN) break;
            int b = batch[gm];
            if (b != cur) {
                if (cur >= 0) atomicAdd(&pool[cur * 64 + col], acc);
                cur = b; acc = 0.f;
            }
            acc += hbuf[r * 68 + col];
        }
        if (cur >= 0) atomicAdd(&pool[cur * 64 + col], acc);
    }
}

__global__ __launch_bounds__(256) void head_kernel(const float* __restrict__ gpool, const float* __restrict__ hls,
                                                   const float* __restrict__ W1, const float* __restrict__ b1,
                                                   const float* __restrict__ W2, const float* __restrict__ b2,
                                                   const float* __restrict__ W3, const float* __restrict__ b3,
                                                   float* __restrict__ out) {
    __shared__ float gin[64][96];
    __shared__ float r1[64][64];
    __shared__ float r2[64][64];
    int tid = threadIdx.x;
    for (int idx = tid; idx < 64 * 96; idx += 256) {
        int g = idx / 96, j = idx % 96;
        gin[g][j] = (j < 64) ? gpool[g * 64 + j] : hls[g * 32 + (j - 64)];
    }
    __syncthreads();
    for (int idx = tid; idx < 64 * 64; idx += 256) {
        int g = idx / 64, j = idx % 64;
        float acc = b1[j];
        for (int k = 0; k < 96; ++k) acc = fmaf(gin[g][k], W1[k * 64 + j], acc);
        r1[g][j] = fmaxf(acc, 0.f);
    }
    __syncthreads();
    for (int idx = tid; idx < 64 * 64; idx += 256) {
        int g = idx / 64, j = idx % 64;
        float acc = b2[j];
        for (int k = 0; k < 64; ++k) acc = fmaf(r1[g][k], W2[k * 64 + j], acc);
        r2[g][j] = fmaxf(acc, 0.f);
    }
    __syncthreads();
    if (tid < 64) {
        float acc = b3[0];
        for (int k = 0; k < 64; ++k) acc = fmaf(r2[tid][k], W3[k], acc);
        out[tid] = acc;
    }
}

extern "C" void kernel_launch(void* const* d_in, const int* in_sizes, int n_in,
                              void* d_out, int out_size, void* d_ws, size_t ws_size,
                              hipStream_t stream) {
    (void)in_sizes; (void)n_in; (void)out_size; (void)ws_size;
    const float* x     = (const float*)d_in[0];
    const float* eattr = (const float*)d_in[1];
    const float* hls   = (const float*)d_in[2];
    const int*   eidx  = (const int*)d_in[3];
    const int*   batch = (const int*)d_in[4];
    const float* We[2]    = {(const float*)d_in[5],  (const float*)d_in[13]};
    const float* be[2]    = {(const float*)d_in[6],  (const float*)d_in[14]};
    const float* Wpre[2]  = {(const float*)d_in[7],  (const float*)d_in[15]};
    const float* bpre[2]  = {(const float*)d_in[8],  (const float*)d_in[16]};
    const float* Wpost[2] = {(const float*)d_in[9],  (const float*)d_in[17]};
    const float* bpost[2] = {(const float*)d_in[10], (const float*)d_in[18]};
    const float* Wlin[2]  = {(const float*)d_in[11], (const float*)d_in[19]};
    const float* blin[2]  = {(const float*)d_in[12], (const float*)d_in[20]};
    const float* W1 = (const float*)d_in[21]; const float* b1 = (const float*)d_in[22];
    const float* W2 = (const float*)d_in[23]; const float* b2 = (const float*)d_in[24];
    const float* W3 = (const float*)d_in[25]; const float* b3 = (const float*)d_in[26];
    float* out = (float*)d_out;

    char* ws = (char*)d_ws;
    size_t off = 0;
    auto carve = [&](size_t bytes) -> char* {
        char* p = ws + off;
        off = (off + bytes + 255) & ~(size_t)255;
        return p;
    };
    int*      cnt     = (int*)carve((size_t)NN * 4);
    int*      csr_src = (int*)carve((size_t)NN * CAP * 4);
    float2*   csr_ea  = (float2*)carve((size_t)NN * CAP * 8);
    float*    AB      = (float*)carve((size_t)NN * 256 * 4);
    ushort_t* agg_hi  = (ushort_t*)carve((size_t)NN * 512 * 2);
    ushort_t* agg_lo  = (ushort_t*)carve((size_t)NN * 512 * 2);
    float2*   sc      = (float2*)carve((size_t)NN * 8);
    ushort_t* xs_hi   = (ushort_t*)carve((size_t)NN * 32 * 2);
    ushort_t* xs_lo   = (ushort_t*)carve((size_t)NN * 32 * 2);
    float*    h1      = (float*)carve((size_t)NN * 64 * 4);
    ushort_t* h1_hi   = (ushort_t*)carve((size_t)NN * 64 * 2);
    ushort_t* h1_lo   = (ushort_t*)carve((size_t)NN * 64 * 2);
    float*    U       = (float*)carve(256 * 4);
    float*    Wab     = (float*)carve(16384 * 4);
    float*    bias_ab = (float*)carve(256 * 4);
    ushort_t* Bh      = (ushort_t*)carve((size_t)192 * 576 * 2);
    ushort_t* Bl      = (ushort_t*)carve((size_t)192 * 576 * 2);
    float*    bias_zf = (float*)carve(64 * 4);
    float*    pool    = (float*)carve(64 * 64 * 4);

    const int MB128 = (NN + 127) / 128;  // 391
    const int SMEM_MAIN = (128 * 40 + 192 * 40) * 2;      // 25600
    const int SMEM_POOL = 128 * 68 * 4;                   // 34816 (> SMEM_MAIN, aliases)

    zero_init<<<(NN + 255) / 256, 256, 0, stream>>>(cnt, pool);
    build_csr<<<(EE + 255) / 256, 256, 0, stream>>>(eidx, eattr, cnt, csr_src, csr_ea);
    split_x<<<(NN * 32 + 255) / 256, 256, 0, stream>>>(x, xs_hi, xs_lo, NN * 32);

    // ---------------- layer 0 (F=32, KT=288) ----------------
    prep_ab<32><<<1, 256, 0, stream>>>(We[0], be[0], Wpre[0], bpre[0], U, Wab, bias_ab);
    prep_zf<32><<<12, 256, 0, stream>>>(Wpost[0], Wlin[0], bpost[0], blin[0], Bh, Bl, bias_zf);
    gemm_bias<<<dim3(MB128, 2), 256, 0, stream>>>(x, Wab, bias_ab, AB, NN, 32, 128);
    aggregate<32><<<(NN + 3) / 4, 256, 0, stream>>>(AB, cnt, csr_src, csr_ea, U, agg_hi, agg_lo, sc);
    gemm_zf<32, false><<<MB128, 256, SMEM_MAIN, stream>>>(xs_hi, xs_lo, agg_hi, agg_lo, Bh, Bl,
                                                          bias_zf, sc, h1, h1_hi, h1_lo, batch, pool);

    // ---------------- layer 1 (F=64, KT=576) ----------------
    prep_ab<64><<<1, 256, 0, stream>>>(We[1], be[1], Wpre[1], bpre[1], U, Wab, bias_ab);
    prep_zf<64><<<12, 256, 0, stream>>>(Wpost[1], Wlin[1], bpost[1], blin[1], Bh, Bl, bias_zf);
    gemm_bias<<<dim3(MB128, 4), 256, 0, stream>>>(h1, Wab, bias_ab, AB, NN, 64, 256);
    aggregate<64><<<(2 * NN + 3) / 4, 256, 0, stream>>>(AB, cnt, csr_src, csr_ea, U, agg_hi, agg_lo, sc);
    gemm_zf<64, true><<<MB128, 256, SMEM_POOL, stream>>>(h1_hi, h1_lo, agg_hi, agg_lo, Bh, Bl,
                                                         bias_zf, sc, nullptr, nullptr, nullptr, batch, pool);

    // ---------------- head ----------------
    head_kernel<<<1, 256, 0, stream>>>(pool, hls, W1, b1, W2, b2, W3, b3, out);
}

// Round 5
// 562.053 us; speedup vs baseline: 1.0330x; 1.0330x over previous
//
#include <hip/hip_runtime.h>
#include <math.h>
#include <float.h>

// Problem constants (HierNet_55705725829422)
#define NN 50000      // nodes
#define EE 800000     // edges
#define CAP 64        // max in-degree capacity (Poisson(16): P(>=64) ~ 1e-19)

typedef unsigned short ushort_t;
typedef short short8 __attribute__((ext_vector_type(8)));
typedef float floatx4 __attribute__((ext_vector_type(4)));

__device__ __constant__ float kAVG_LOG = 2.8332133440562162f; // log(17)

__device__ inline ushort_t f2bf(float v) {
    union { float f; unsigned u; } x; x.f = v;
    unsigned r = x.u + 0x7fffu + ((x.u >> 16) & 1u);
    return (ushort_t)(r >> 16);
}
__device__ inline float bf2f(ushort_t b) {
    union { unsigned u; float f; } x; x.u = ((unsigned)b) << 16; return x.f;
}
__device__ inline void splitbf(float v, ushort_t& hi, ushort_t& lo) {
    hi = f2bf(v);
    lo = f2bf(v - bf2f(hi));
}

__global__ __launch_bounds__(256) void zero_init(int* cnt, float* pool) {
    int i = blockIdx.x * 256 + threadIdx.x;
    if (i < NN) cnt[i] = 0;
    if (i < 64 * 64) pool[i] = 0.f;
}

__global__ __launch_bounds__(256) void build_csr(const int* __restrict__ ei, const float* __restrict__ ea,
                                                 int* __restrict__ cnt, int* __restrict__ csr_src,
                                                 float2* __restrict__ csr_ea) {
    int e = blockIdx.x * 256 + threadIdx.x;
    if (e >= EE) return;
    int s = ei[e];
    int d = ei[EE + e];
    float2 v = *(const float2*)(ea + 2 * e);
    int p = atomicAdd(&cnt[d], 1);
    if (p < CAP) {
        csr_src[d * CAP + p] = s;
        csr_ea[d * CAP + p] = v;
    }
}

__global__ __launch_bounds__(256) void split_x(const float* __restrict__ x, ushort_t* __restrict__ hi,
                                               ushort_t* __restrict__ lo, int n) {
    int i = blockIdx.x * 256 + threadIdx.x;
    if (i < n) splitbf(x[i], hi[i], lo[i]);
}

// per-layer A/B-projection weight prep: U, Wab (fp32, for fp32 gemm_bias), bias_ab
template <int F>
__global__ __launch_bounds__(256) void prep_ab(const float* __restrict__ We, const float* __restrict__ be,
                                               const float* __restrict__ Wpre, const float* __restrict__ bpre,
                                               float* __restrict__ U, float* __restrict__ Wab,
                                               float* __restrict__ bias_ab) {
    const int TF = 2 * F;
    int tid = threadIdx.x;
    for (int idx = tid; idx < 2 * TF; idx += 256) {
        int c = idx / TF, f = idx % TF;
        int t = f / F, o = f % F;
        float s = 0.f;
        for (int g = 0; g < F; ++g)
            s += We[c * F + g] * Wpre[((size_t)t * 3 * F + 2 * F + g) * F + o];
        U[idx] = s;
    }
    for (int idx = tid; idx < F * 2 * TF; idx += 256) {
        int g = idx / (2 * TF), cc = idx % (2 * TF);
        int t, o, row;
        if (cc < TF) { t = cc / F; o = cc % F; row = g; }
        else { int c2 = cc - TF; t = c2 / F; o = c2 % F; row = F + g; }
        Wab[idx] = Wpre[((size_t)t * 3 * F + row) * F + o];
    }
    for (int cc = tid; cc < 2 * TF; cc += 256) {
        float v = 0.f;
        if (cc < TF) {
            int t = cc / F, o = cc % F;
            float s = 0.f;
            for (int g = 0; g < F; ++g)
                s += be[g] * Wpre[((size_t)t * 3 * F + 2 * F + g) * F + o];
            v = s + bpre[t * F + o];
        }
        bias_ab[cc] = v;
    }
}

// Folded Z/final weights, split to bf16 hi/lo, stored COL-MAJOR [192 cols][KT]
template <int F>
__global__ __launch_bounds__(256) void prep_zf(const float* __restrict__ Wpost, const float* __restrict__ Wlin,
                                               const float* __restrict__ bpost, const float* __restrict__ blin,
                                               ushort_t* __restrict__ Bh, ushort_t* __restrict__ Bl,
                                               float* __restrict__ bias_zf) {
    const int KT = 9 * F;
    int bx = blockIdx.x;  // 12 blocks x 16 cols
    int tid = threadIdx.x;
    for (int idx = tid; idx < 16 * KT; idx += 256) {
        int jj = idx / KT, k = idx % KT;
        int jg = bx * 16 + jj;
        int b = jg >> 6, j = jg & 63;
        float v = 0.f;
        if (k < F) {
            if (b == 0) {
                float s = 0.f;
                for (int t = 0; t < 2; ++t)
                    for (int c = 0; c < 32; ++c)
                        s += Wpost[((size_t)t * 13 * F + k) * 32 + c] * Wlin[(t * 32 + c) * 64 + j];
                v = s;
            }
        } else {
            int r = k - F;
            int t = r / (4 * F), rr = r - t * 4 * F;
            float s = 0.f;
            for (int c = 0; c < 32; ++c)
                s += Wpost[((size_t)t * 13 * F + F + b * 4 * F + rr) * 32 + c] * Wlin[(t * 32 + c) * 64 + j];
            v = s;
        }
        ushort_t h_, l_;
        splitbf(v, h_, l_);
        Bh[(size_t)jg * KT + k] = h_;
        Bl[(size_t)jg * KT + k] = l_;
    }
    if (bx == 0) {
        for (int j = tid; j < 64; j += 256) {
            float s = blin[j];
            for (int t = 0; t < 2; ++t)
                for (int c = 0; c < 32; ++c)
                    s += bpost[t * 32 + c] * Wlin[(t * 32 + c) * 64 + j];
            bias_zf[j] = s;
        }
    }
}

// fp32 GEMM for A/B projection: C[MxN] = A[MxK]@B[KxN] + bias. Tile 128x64, micro 8x4.
__global__ __launch_bounds__(256) void gemm_bias(const float* __restrict__ A, const float* __restrict__ B,
                                                 const float* __restrict__ bias, float* __restrict__ C,
                                                 int M, int K, int Ncols) {
    __shared__ float As[32][132];
    __shared__ float Bs[32][68];
    int m0 = blockIdx.x * 128, c0 = blockIdx.y * 64;
    int tid = threadIdx.x;
    int tx = tid & 15, ty = tid >> 4;
    int ms = tid >> 3, u = tid & 7;
    float acc[8][4] = {};
    for (int k0 = 0; k0 < K; k0 += 32) {
#pragma unroll
        for (int p = 0; p < 4; ++p) {
            int m = ms + 32 * p;
            int gm = m0 + m;
            float4 v = make_float4(0.f, 0.f, 0.f, 0.f);
            if (gm < M) v = *(const float4*)(A + (size_t)gm * K + k0 + u * 4);
            As[u * 4 + 0][m] = v.x; As[u * 4 + 1][m] = v.y;
            As[u * 4 + 2][m] = v.z; As[u * 4 + 3][m] = v.w;
        }
#pragma unroll
        for (int p = 0; p < 2; ++p) {
            int idx = tid + 256 * p;
            int kk = idx >> 4, q = idx & 15;
            *(float4*)&Bs[kk][q * 4] = *(const float4*)(B + (size_t)(k0 + kk) * Ncols + c0 + q * 4);
        }
        __syncthreads();
#pragma unroll 8
        for (int k = 0; k < 32; ++k) {
            float a0[8], b0[4];
            *(float4*)&a0[0] = *(const float4*)&As[k][ty * 8];
            *(float4*)&a0[4] = *(const float4*)&As[k][ty * 8 + 4];
            *(float4*)&b0[0] = *(const float4*)&Bs[k][tx * 4];
#pragma unroll
            for (int i = 0; i < 8; ++i)
#pragma unroll
                for (int j = 0; j < 4; ++j) acc[i][j] = fmaf(a0[i], b0[j], acc[i][j]);
        }
        __syncthreads();
    }
    float bj[4];
#pragma unroll
    for (int j = 0; j < 4; ++j) bj[j] = bias[c0 + tx * 4 + j];
#pragma unroll
    for (int i = 0; i < 8; ++i) {
        int gm = m0 + ty * 8 + i;
        if (gm >= M) continue;
        float4 v = make_float4(acc[i][0] + bj[0], acc[i][1] + bj[1], acc[i][2] + bj[2], acc[i][3] + bj[3]);
        *(float4*)(C + (size_t)gm * Ncols + c0 + tx * 4) = v;
    }
}

// aggregate: one wave per (node, 64-feature half). Emits agg as bf16 hi/lo splits.
template <int F>
__global__ __launch_bounds__(256) void aggregate(const float* __restrict__ AB, const int* __restrict__ cnt,
                                                 const int* __restrict__ csr_src, const float2* __restrict__ csr_ea,
                                                 const float* __restrict__ U, ushort_t* __restrict__ agg_hi,
                                                 ushort_t* __restrict__ agg_lo, float2* __restrict__ sc) {
    const int TF = 2 * F;
    const int SPN = TF / 64;
    int lane = threadIdx.x & 63;
    int slot = blockIdx.x * 4 + (threadIdx.x >> 6);
    int n = slot / SPN;
    int half = slot - n * SPN;
    if (n >= NN) return;
    int f = half * 64 + lane;

    float base = AB[(size_t)n * (2 * TF) + f];
    float u0 = U[f], u1 = U[TF + f];
    int deg = cnt[n];
    int ec = deg < CAP ? deg : CAP;

    float sum = 0.f, sq = 0.f, mn = FLT_MAX, mx = -FLT_MAX;
    if (ec > 0) {
        int ebase = n * CAP;
        int myi = lane < ec ? lane : ec - 1;
        int msrc = csr_src[ebase + myi];
        float2 mea = csr_ea[ebase + myi];
        const float* Bcol = AB + TF + f;
        for (int e = 0; e < ec; e += 8) {
            int sb[8]; float ex[8], ey[8], v[8];
#pragma unroll
            for (int i = 0; i < 8; ++i) {
                sb[i] = __shfl(msrc, e + i);
                ex[i] = __shfl(mea.x, e + i);
                ey[i] = __shfl(mea.y, e + i);
            }
#pragma unroll
            for (int i = 0; i < 8; ++i)
                if (e + i < ec) v[i] = Bcol[(size_t)sb[i] * (2 * TF)];
#pragma unroll
            for (int i = 0; i < 8; ++i) {
                if (e + i < ec) {
                    float q = fmaf(ex[i], u0, fmaf(ey[i], u1, v[i]));
                    sum += q;
                    sq = fmaf(q, q, sq);
                    mn = fminf(mn, q);
                    mx = fmaxf(mx, q);
                }
            }
        }
    }
    float d = (float)(deg > 1 ? deg : 1);
    float inv_d = 1.f / d;
    float mean_q = sum * inv_d;
    float var = sq * inv_d - mean_q * mean_q;
    float stdv = sqrtf(fmaxf(var, 0.f) + 1e-5f);
    bool has = deg > 0;
    float mean = has ? base + mean_q : 0.f;
    float vmn = has ? base + mn : 0.f;
    float vmx = has ? base + mx : 0.f;
    int t = f / F, o = f - t * F;
    size_t rowb = (size_t)n * (4 * TF) + (size_t)t * (4 * F);
    ushort_t h_, l_;
    splitbf(mean, h_, l_); agg_hi[rowb + o] = h_;         agg_lo[rowb + o] = l_;
    splitbf(vmn,  h_, l_); agg_hi[rowb + F + o] = h_;     agg_lo[rowb + F + o] = l_;
    splitbf(vmx,  h_, l_); agg_hi[rowb + 2 * F + o] = h_; agg_lo[rowb + 2 * F + o] = l_;
    splitbf(stdv, h_, l_); agg_hi[rowb + 3 * F + o] = h_; agg_lo[rowb + 3 * F + o] = l_;
    if (half == 0 && lane == 0) {
        float logd = logf(d + 1.f);
        sc[n] = make_float2(logd / kAVG_LOG, kAVG_LOG / logd);
    }
}

// MFMA split-bf16 merged Z+final GEMM, single K-pass (hi/lo tiles co-resident).
// A' = [x | agg] [N x 9F] (hi/lo). B [9F x 192] col-major hi/lo.
// Y = Ah@Bh + Ah@Bl + Al@Bh (all into one acc). h = relu(Y0 + s1*Y1 + s2*Y2 + bias).
// Block tile 64x192, 4 waves; wave = 16 rows x 192 cols (12 16x16 frags).
template <int F, bool POOL>
__global__ __launch_bounds__(256) void gemm_zf(
    const ushort_t* __restrict__ xs_hi, const ushort_t* __restrict__ xs_lo,
    const ushort_t* __restrict__ agg_hi, const ushort_t* __restrict__ agg_lo,
    const ushort_t* __restrict__ Bh, const ushort_t* __restrict__ Bl,
    const float* __restrict__ bias_zf, const float2* __restrict__ sc,
    float* __restrict__ H, ushort_t* __restrict__ H_hi, ushort_t* __restrict__ H_lo,
    const int* __restrict__ batch, float* __restrict__ pool) {
    const int KT = 9 * F;
    extern __shared__ char smem[];
    ushort_t* Ah_s = (ushort_t*)smem;        // [64][40]
    ushort_t* Al_s = Ah_s + 64 * 40;         // [64][40]
    ushort_t* Bh_s = Al_s + 64 * 40;         // [192][40]
    ushort_t* Bl_s = Bh_s + 192 * 40;        // [192][40]
    float* hbuf = (float*)smem;              // POOL alias [64][68]

    int m0 = blockIdx.x * 64;
    int tid = threadIdx.x;
    int lane = tid & 63;
    int wave = tid >> 6;
    int ln = lane & 15, quad = lane >> 4;
    int wrow = wave * 16;

    floatx4 acc[12];
#pragma unroll
    for (int i = 0; i < 12; ++i) acc[i] = (floatx4)(0.f);

    // A staging indices: 256 chunks cover 64 rows x 4 sg (1/thread/half)
    int arow = tid >> 2, asg = tid & 3;
    int agm = m0 + arow;

    for (int k0 = 0; k0 < KT; k0 += 32) {
        // stage A hi+lo
        {
            int c0 = k0 + asg * 8;
            short8 vh = {0, 0, 0, 0, 0, 0, 0, 0};
            short8 vl = {0, 0, 0, 0, 0, 0, 0, 0};
            if (agm < NN) {
                if (c0 < F) {
                    vh = *(const short8*)(xs_hi + (size_t)agm * F + c0);
                    vl = *(const short8*)(xs_lo + (size_t)agm * F + c0);
                } else {
                    vh = *(const short8*)(agg_hi + (size_t)agm * 8 * F + (c0 - F));
                    vl = *(const short8*)(agg_lo + (size_t)agm * 8 * F + (c0 - F));
                }
            }
            *(short8*)&Ah_s[arow * 40 + asg * 8] = vh;
            *(short8*)&Al_s[arow * 40 + asg * 8] = vl;
        }
        // stage B hi+lo: 768 chunks each, 3/thread
#pragma unroll
        for (int p = 0; p < 3; ++p) {
            int idx = tid + 256 * p;
            int col = idx >> 2, sg = idx & 3;
            *(short8*)&Bh_s[col * 40 + sg * 8] = *(const short8*)(Bh + (size_t)col * KT + k0 + sg * 8);
            *(short8*)&Bl_s[col * 40 + sg * 8] = *(const short8*)(Bl + (size_t)col * KT + k0 + sg * 8);
        }
        __syncthreads();
        short8 ah = *(short8*)&Ah_s[(wrow + ln) * 40 + quad * 8];
        short8 al = *(short8*)&Al_s[(wrow + ln) * 40 + quad * 8];
#pragma unroll
        for (int nt = 0; nt < 12; ++nt) {
            short8 bh = *(short8*)&Bh_s[(nt * 16 + ln) * 40 + quad * 8];
            short8 bl = *(short8*)&Bl_s[(nt * 16 + ln) * 40 + quad * 8];
            acc[nt] = __builtin_amdgcn_mfma_f32_16x16x32_bf16(ah, bh, acc[nt], 0, 0, 0);
            acc[nt] = __builtin_amdgcn_mfma_f32_16x16x32_bf16(ah, bl, acc[nt], 0, 0, 0);
            acc[nt] = __builtin_amdgcn_mfma_f32_16x16x32_bf16(al, bh, acc[nt], 0, 0, 0);
        }
        __syncthreads();
    }

    float bj[4];
#pragma unroll
    for (int j = 0; j < 4; ++j) bj[j] = bias_zf[j * 16 + ln];

    if (POOL) __syncthreads();  // smem reuse as hbuf

#pragma unroll
    for (int reg = 0; reg < 4; ++reg) {
        int r = wrow + quad * 4 + reg;
        int gm = m0 + r;
        float2 s = make_float2(0.f, 0.f);
        if (gm < NN) s = sc[gm];
#pragma unroll
        for (int j = 0; j < 4; ++j) {
            float y = acc[j][reg] + s.x * acc[j + 4][reg] + s.y * acc[j + 8][reg] + bj[j];
            y = fmaxf(y, 0.f);
            int col = j * 16 + ln;
            if (POOL) {
                hbuf[r * 68 + col] = (gm < NN) ? y : 0.f;
            } else if (gm < NN) {
                H[(size_t)gm * 64 + col] = y;
                ushort_t h_, l_;
                splitbf(y, h_, l_);
                H_hi[(size_t)gm * 64 + col] = h_;
                H_lo[(size_t)gm * 64 + col] = l_;
            }
        }
    }
    if (POOL) {
        __syncthreads();
        int col = tid & 63, grp = tid >> 6;
        float a = 0.f;
        int cur = -1;
        for (int i = 0; i < 16; ++i) {
            int r = grp * 16 + i;
            int gm = m0 + r;
            if (gm >= NN) break;
            int b = batch[gm];
            if (b != cur) {
                if (cur >= 0) atomicAdd(&pool[cur * 64 + col], a);
                cur = b; a = 0.f;
            }
            a += hbuf[r * 68 + col];
        }
        if (cur >= 0) atomicAdd(&pool[cur * 64 + col], a);
    }
}

__global__ __launch_bounds__(256) void head_kernel(const float* __restrict__ gpool, const float* __restrict__ hls,
                                                   const float* __restrict__ W1, const float* __restrict__ b1,
                                                   const float* __restrict__ W2, const float* __restrict__ b2,
                                                   const float* __restrict__ W3, const float* __restrict__ b3,
                                                   float* __restrict__ out) {
    __shared__ float gin[64][96];
    __shared__ float r1[64][64];
    __shared__ float r2[64][64];
    int tid = threadIdx.x;
    for (int idx = tid; idx < 64 * 96; idx += 256) {
        int g = idx / 96, j = idx % 96;
        gin[g][j] = (j < 64) ? gpool[g * 64 + j] : hls[g * 32 + (j - 64)];
    }
    __syncthreads();
    for (int idx = tid; idx < 64 * 64; idx += 256) {
        int g = idx / 64, j = idx % 64;
        float acc = b1[j];
        for (int k = 0; k < 96; ++k) acc = fmaf(gin[g][k], W1[k * 64 + j], acc);
        r1[g][j] = fmaxf(acc, 0.f);
    }
    __syncthreads();
    for (int idx = tid; idx < 64 * 64; idx += 256) {
        int g = idx / 64, j = idx % 64;
        float acc = b2[j];
        for (int k = 0; k < 64; ++k) acc = fmaf(r1[g][k], W2[k * 64 + j], acc);
        r2[g][j] = fmaxf(acc, 0.f);
    }
    __syncthreads();
    if (tid < 64) {
        float acc = b3[0];
        for (int k = 0; k < 64; ++k) acc = fmaf(r2[tid][k], W3[k], acc);
        out[tid] = acc;
    }
}

extern "C" void kernel_launch(void* const* d_in, const int* in_sizes, int n_in,
                              void* d_out, int out_size, void* d_ws, size_t ws_size,
                              hipStream_t stream) {
    (void)in_sizes; (void)n_in; (void)out_size; (void)ws_size;
    const float* x     = (const float*)d_in[0];
    const float* eattr = (const float*)d_in[1];
    const float* hls   = (const float*)d_in[2];
    const int*   eidx  = (const int*)d_in[3];
    const int*   batch = (const int*)d_in[4];
    const float* We[2]    = {(const float*)d_in[5],  (const float*)d_in[13]};
    const float* be[2]    = {(const float*)d_in[6],  (const float*)d_in[14]};
    const float* Wpre[2]  = {(const float*)d_in[7],  (const float*)d_in[15]};
    const float* bpre[2]  = {(const float*)d_in[8],  (const float*)d_in[16]};
    const float* Wpost[2] = {(const float*)d_in[9],  (const float*)d_in[17]};
    const float* bpost[2] = {(const float*)d_in[10], (const float*)d_in[18]};
    const float* Wlin[2]  = {(const float*)d_in[11], (const float*)d_in[19]};
    const float* blin[2]  = {(const float*)d_in[12], (const float*)d_in[20]};
    const float* W1 = (const float*)d_in[21]; const float* b1 = (const float*)d_in[22];
    const float* W2 = (const float*)d_in[23]; const float* b2 = (const float*)d_in[24];
    const float* W3 = (const float*)d_in[25]; const float* b3 = (const float*)d_in[26];
    float* out = (float*)d_out;

    char* ws = (char*)d_ws;
    size_t off = 0;
    auto carve = [&](size_t bytes) -> char* {
        char* p = ws + off;
        off = (off + bytes + 255) & ~(size_t)255;
        return p;
    };
    int*      cnt     = (int*)carve((size_t)NN * 4);
    int*      csr_src = (int*)carve((size_t)NN * CAP * 4);
    float2*   csr_ea  = (float2*)carve((size_t)NN * CAP * 8);
    float*    AB      = (float*)carve((size_t)NN * 256 * 4);
    ushort_t* agg_hi  = (ushort_t*)carve((size_t)NN * 512 * 2);
    ushort_t* agg_lo  = (ushort_t*)carve((size_t)NN * 512 * 2);
    float2*   sc      = (float2*)carve((size_t)NN * 8);
    ushort_t* xs_hi   = (ushort_t*)carve((size_t)NN * 32 * 2);
    ushort_t* xs_lo   = (ushort_t*)carve((size_t)NN * 32 * 2);
    float*    h1      = (float*)carve((size_t)NN * 64 * 4);
    ushort_t* h1_hi   = (ushort_t*)carve((size_t)NN * 64 * 2);
    ushort_t* h1_lo   = (ushort_t*)carve((size_t)NN * 64 * 2);
    float*    U       = (float*)carve(256 * 4);
    float*    Wab     = (float*)carve(16384 * 4);
    float*    bias_ab = (float*)carve(256 * 4);
    ushort_t* Bh      = (ushort_t*)carve((size_t)192 * 576 * 2);
    ushort_t* Bl      = (ushort_t*)carve((size_t)192 * 576 * 2);
    float*    bias_zf = (float*)carve(64 * 4);
    float*    pool    = (float*)carve(64 * 64 * 4);

    const int MB128 = (NN + 127) / 128;  // 391
    const int MB64  = (NN + 63) / 64;    // 782
    const int SMEM_ZF = (64 * 40 + 64 * 40 + 192 * 40 + 192 * 40) * 2;  // 40960

    zero_init<<<(NN + 255) / 256, 256, 0, stream>>>(cnt, pool);
    build_csr<<<(EE + 255) / 256, 256, 0, stream>>>(eidx, eattr, cnt, csr_src, csr_ea);
    split_x<<<(NN * 32 + 255) / 256, 256, 0, stream>>>(x, xs_hi, xs_lo, NN * 32);

    // ---------------- layer 0 (F=32, KT=288) ----------------
    prep_ab<32><<<1, 256, 0, stream>>>(We[0], be[0], Wpre[0], bpre[0], U, Wab, bias_ab);
    prep_zf<32><<<12, 256, 0, stream>>>(Wpost[0], Wlin[0], bpost[0], blin[0], Bh, Bl, bias_zf);
    gemm_bias<<<dim3(MB128, 2), 256, 0, stream>>>(x, Wab, bias_ab, AB, NN, 32, 128);
    aggregate<32><<<(NN + 3) / 4, 256, 0, stream>>>(AB, cnt, csr_src, csr_ea, U, agg_hi, agg_lo, sc);
    gemm_zf<32, false><<<MB64, 256, SMEM_ZF, stream>>>(xs_hi, xs_lo, agg_hi, agg_lo, Bh, Bl,
                                                       bias_zf, sc, h1, h1_hi, h1_lo, batch, pool);

    // ---------------- layer 1 (F=64, KT=576) ----------------
    prep_ab<64><<<1, 256, 0, stream>>>(We[1], be[1], Wpre[1], bpre[1], U, Wab, bias_ab);
    prep_zf<64><<<12, 256, 0, stream>>>(Wpost[1], Wlin[1], bpost[1], blin[1], Bh, Bl, bias_zf);
    gemm_bias<<<dim3(MB128, 4), 256, 0, stream>>>(h1, Wab, bias_ab, AB, NN, 64, 256);
    aggregate<64><<<(2 * NN + 3) / 4, 256, 0, stream>>>(AB, cnt, csr_src, csr_ea, U, agg_hi, agg_lo, sc);
    gemm_zf<64, true><<<MB64, 256, SMEM_ZF, stream>>>(h1_hi, h1_lo, agg_hi, agg_lo, Bh, Bl,
                                                      bias_zf, sc, nullptr, nullptr, nullptr, batch, pool);

    // ---------------- head ----------------
    head_kernel<<<1, 256, 0, stream>>>(pool, hls, W1, b1, W2, b2, W3, b3, out);
}

// Round 6
// 533.387 us; speedup vs baseline: 1.0885x; 1.0537x over previous
//
#include <hip/hip_runtime.h>
#include <math.h>
#include <float.h>

// Problem constants (HierNet_55705725829422)
#define NN 50000      // nodes
#define EE 800000     // edges
#define CAP 64        // max in-degree capacity (Poisson(16): P(>=64) ~ 1e-19)

typedef unsigned short ushort_t;
typedef short short8 __attribute__((ext_vector_type(8)));
typedef float floatx4 __attribute__((ext_vector_type(4)));

__device__ __constant__ float kAVG_LOG = 2.8332133440562162f; // log(17)

__device__ inline ushort_t f2bf(float v) {
    union { float f; unsigned u; } x; x.f = v;
    unsigned r = x.u + 0x7fffu + ((x.u >> 16) & 1u);
    return (ushort_t)(r >> 16);
}
__device__ inline float bf2f(ushort_t b) {
    union { unsigned u; float f; } x; x.u = ((unsigned)b) << 16; return x.f;
}
__device__ inline float bitsf(unsigned u) {
    union { unsigned u; float f; } x; x.u = u; return x.f;
}
__device__ inline void splitbf(float v, ushort_t& hi, ushort_t& lo) {
    hi = f2bf(v);
    lo = f2bf(v - bf2f(hi));
}

__global__ __launch_bounds__(256) void zero_init(int* cnt, float* pool) {
    int i = blockIdx.x * 256 + threadIdx.x;
    if (i < NN) cnt[i] = 0;
    if (i < 64 * 64) pool[i] = 0.f;
}

__global__ __launch_bounds__(256) void build_csr(const int* __restrict__ ei, const float* __restrict__ ea,
                                                 int* __restrict__ cnt, int* __restrict__ csr_src,
                                                 float2* __restrict__ csr_ea) {
    int e = blockIdx.x * 256 + threadIdx.x;
    if (e >= EE) return;
    int s = ei[e];
    int d = ei[EE + e];
    float2 v = *(const float2*)(ea + 2 * e);
    int p = atomicAdd(&cnt[d], 1);
    if (p < CAP) {
        csr_src[d * CAP + p] = s;
        csr_ea[d * CAP + p] = v;
    }
}

__global__ __launch_bounds__(256) void split_x(const float* __restrict__ x, ushort_t* __restrict__ hi,
                                               ushort_t* __restrict__ lo, int n) {
    int i = blockIdx.x * 256 + threadIdx.x;
    if (i < n) splitbf(x[i], hi[i], lo[i]);
}

// per-layer A/B-projection weight prep: U, Wab (fp32), bias_ab
template <int F>
__global__ __launch_bounds__(256) void prep_ab(const float* __restrict__ We, const float* __restrict__ be,
                                               const float* __restrict__ Wpre, const float* __restrict__ bpre,
                                               float* __restrict__ U, float* __restrict__ Wab,
                                               float* __restrict__ bias_ab) {
    const int TF = 2 * F;
    int tid = threadIdx.x;
    for (int idx = tid; idx < 2 * TF; idx += 256) {
        int c = idx / TF, f = idx % TF;
        int t = f / F, o = f % F;
        float s = 0.f;
        for (int g = 0; g < F; ++g)
            s += We[c * F + g] * Wpre[((size_t)t * 3 * F + 2 * F + g) * F + o];
        U[idx] = s;
    }
    for (int idx = tid; idx < F * 2 * TF; idx += 256) {
        int g = idx / (2 * TF), cc = idx % (2 * TF);
        int t, o, row;
        if (cc < TF) { t = cc / F; o = cc % F; row = g; }
        else { int c2 = cc - TF; t = c2 / F; o = c2 % F; row = F + g; }
        Wab[idx] = Wpre[((size_t)t * 3 * F + row) * F + o];
    }
    for (int cc = tid; cc < 2 * TF; cc += 256) {
        float v = 0.f;
        if (cc < TF) {
            int t = cc / F, o = cc % F;
            float s = 0.f;
            for (int g = 0; g < F; ++g)
                s += be[g] * Wpre[((size_t)t * 3 * F + 2 * F + g) * F + o];
            v = s + bpre[t * F + o];
        }
        bias_ab[cc] = v;
    }
}

// Folded Z/final weights, split to bf16 hi/lo, stored COL-MAJOR [192 cols][KT]
template <int F>
__global__ __launch_bounds__(256) void prep_zf(const float* __restrict__ Wpost, const float* __restrict__ Wlin,
                                               const float* __restrict__ bpost, const float* __restrict__ blin,
                                               ushort_t* __restrict__ Bh, ushort_t* __restrict__ Bl,
                                               float* __restrict__ bias_zf) {
    const int KT = 9 * F;
    int bx = blockIdx.x;  // 12 blocks x 16 cols
    int tid = threadIdx.x;
    for (int idx = tid; idx < 16 * KT; idx += 256) {
        int jj = idx / KT, k = idx % KT;
        int jg = bx * 16 + jj;
        int b = jg >> 6, j = jg & 63;
        float v = 0.f;
        if (k < F) {
            if (b == 0) {
                float s = 0.f;
                for (int t = 0; t < 2; ++t)
                    for (int c = 0; c < 32; ++c)
                        s += Wpost[((size_t)t * 13 * F + k) * 32 + c] * Wlin[(t * 32 + c) * 64 + j];
                v = s;
            }
        } else {
            int r = k - F;
            int t = r / (4 * F), rr = r - t * 4 * F;
            float s = 0.f;
            for (int c = 0; c < 32; ++c)
                s += Wpost[((size_t)t * 13 * F + F + b * 4 * F + rr) * 32 + c] * Wlin[(t * 32 + c) * 64 + j];
            v = s;
        }
        ushort_t h_, l_;
        splitbf(v, h_, l_);
        Bh[(size_t)jg * KT + k] = h_;
        Bl[(size_t)jg * KT + k] = l_;
    }
    if (bx == 0) {
        for (int j = tid; j < 64; j += 256) {
            float s = blin[j];
            for (int t = 0; t < 2; ++t)
                for (int c = 0; c < 32; ++c)
                    s += bpost[t * 32 + c] * Wlin[(t * 32 + c) * 64 + j];
            bias_zf[j] = s;
        }
    }
}

// fp32 GEMM: [Ca | Cb] = A[MxK]@B[KxN] + bias. Columns < bstart -> fp32 Ca; >= bstart -> bf16 Cb.
// Tile 128x64, micro 8x4. bstart multiple of 64.
__global__ __launch_bounds__(256) void gemm_bias(const float* __restrict__ A, const float* __restrict__ B,
                                                 const float* __restrict__ bias, float* __restrict__ Ca,
                                                 ushort_t* __restrict__ Cb, int M, int K, int Ncols, int bstart) {
    __shared__ float As[32][132];
    __shared__ float Bs[32][68];
    int m0 = blockIdx.x * 128, c0 = blockIdx.y * 64;
    int tid = threadIdx.x;
    int tx = tid & 15, ty = tid >> 4;
    int ms = tid >> 3, u = tid & 7;
    float acc[8][4] = {};
    for (int k0 = 0; k0 < K; k0 += 32) {
#pragma unroll
        for (int p = 0; p < 4; ++p) {
            int m = ms + 32 * p;
            int gm = m0 + m;
            float4 v = make_float4(0.f, 0.f, 0.f, 0.f);
            if (gm < M) v = *(const float4*)(A + (size_t)gm * K + k0 + u * 4);
            As[u * 4 + 0][m] = v.x; As[u * 4 + 1][m] = v.y;
            As[u * 4 + 2][m] = v.z; As[u * 4 + 3][m] = v.w;
        }
#pragma unroll
        for (int p = 0; p < 2; ++p) {
            int idx = tid + 256 * p;
            int kk = idx >> 4, q = idx & 15;
            *(float4*)&Bs[kk][q * 4] = *(const float4*)(B + (size_t)(k0 + kk) * Ncols + c0 + q * 4);
        }
        __syncthreads();
#pragma unroll 8
        for (int k = 0; k < 32; ++k) {
            float a0[8], b0[4];
            *(float4*)&a0[0] = *(const float4*)&As[k][ty * 8];
            *(float4*)&a0[4] = *(const float4*)&As[k][ty * 8 + 4];
            *(float4*)&b0[0] = *(const float4*)&Bs[k][tx * 4];
#pragma unroll
            for (int i = 0; i < 8; ++i)
#pragma unroll
                for (int j = 0; j < 4; ++j) acc[i][j] = fmaf(a0[i], b0[j], acc[i][j]);
        }
        __syncthreads();
    }
    float bj[4];
#pragma unroll
    for (int j = 0; j < 4; ++j) bj[j] = bias[c0 + tx * 4 + j];
    bool bside = (c0 >= bstart);
    int TFw = bstart;  // row stride of both halves
#pragma unroll
    for (int i = 0; i < 8; ++i) {
        int gm = m0 + ty * 8 + i;
        if (gm >= M) continue;
        float v0 = acc[i][0] + bj[0], v1 = acc[i][1] + bj[1];
        float v2 = acc[i][2] + bj[2], v3 = acc[i][3] + bj[3];
        if (!bside) {
            *(float4*)(Ca + (size_t)gm * TFw + c0 + tx * 4) = make_float4(v0, v1, v2, v3);
        } else {
            ushort4 w;
            w.x = f2bf(v0); w.y = f2bf(v1); w.z = f2bf(v2); w.w = f2bf(v3);
            *(ushort4*)(Cb + (size_t)gm * TFw + (c0 - bstart) + tx * 4) = w;
        }
    }
}

// aggregate: ONE wave per node (FPL = TF/64 features per lane, bf16 gather).
// q = Bsrc_bf16 + ea.x*u0 + ea.y*u1; mean/min/max get +base in epilogue (std shift-invariant).
template <int F>
__global__ __launch_bounds__(256) void aggregate(const float* __restrict__ ABa, const ushort_t* __restrict__ ABb,
                                                 const int* __restrict__ cnt, const int* __restrict__ csr_src,
                                                 const float2* __restrict__ csr_ea, const float* __restrict__ U,
                                                 ushort_t* __restrict__ agg_hi, ushort_t* __restrict__ agg_lo,
                                                 float2* __restrict__ sc) {
    const int TF = 2 * F;
    const int FPL = TF / 64;  // 1 (F=32) or 2 (F=64)
    int lane = threadIdx.x & 63;
    int n = blockIdx.x * 4 + (threadIdx.x >> 6);
    if (n >= NN) return;
    int f0 = FPL * lane;

    float base[FPL], u0[FPL], u1[FPL], sum[FPL], sq[FPL], mn[FPL], mx[FPL];
#pragma unroll
    for (int r = 0; r < FPL; ++r) {
        base[r] = ABa[(size_t)n * TF + f0 + r];
        u0[r] = U[f0 + r];
        u1[r] = U[TF + f0 + r];
        sum[r] = 0.f; sq[r] = 0.f; mn[r] = FLT_MAX; mx[r] = -FLT_MAX;
    }
    int deg = cnt[n];
    int ec = deg < CAP ? deg : CAP;
    if (ec > 0) {
        int ebase = n * CAP;
        int myi = lane < ec ? lane : ec - 1;
        int msrc = csr_src[ebase + myi];
        float2 mea = csr_ea[ebase + myi];
        for (int e = 0; e < ec; e += 8) {
            int sb[8]; float ex[8], ey[8];
            unsigned wv[8];
#pragma unroll
            for (int i = 0; i < 8; ++i) {
                sb[i] = __shfl(msrc, e + i);
                ex[i] = __shfl(mea.x, e + i);
                ey[i] = __shfl(mea.y, e + i);
            }
#pragma unroll
            for (int i = 0; i < 8; ++i) {
                if (e + i < ec) {
                    if (FPL == 2)
                        wv[i] = *(const unsigned*)(ABb + (size_t)sb[i] * TF + f0);
                    else
                        wv[i] = ABb[(size_t)sb[i] * TF + f0];
                }
            }
#pragma unroll
            for (int i = 0; i < 8; ++i) {
                if (e + i < ec) {
                    float v[FPL];
                    if (FPL == 2) {
                        v[0] = bitsf(wv[i] << 16);
                        v[1] = bitsf(wv[i] & 0xffff0000u);
                    } else {
                        v[0] = bitsf(wv[i] << 16);
                    }
#pragma unroll
                    for (int r = 0; r < FPL; ++r) {
                        float q = fmaf(ex[i], u0[r], fmaf(ey[i], u1[r], v[r]));
                        sum[r] += q;
                        sq[r] = fmaf(q, q, sq[r]);
                        mn[r] = fminf(mn[r], q);
                        mx[r] = fmaxf(mx[r], q);
                    }
                }
            }
        }
    }
    float d = (float)(deg > 1 ? deg : 1);
    float inv_d = 1.f / d;
    bool has = deg > 0;
#pragma unroll
    for (int r = 0; r < FPL; ++r) {
        float mean_q = sum[r] * inv_d;
        float var = sq[r] * inv_d - mean_q * mean_q;
        float stdv = sqrtf(fmaxf(var, 0.f) + 1e-5f);
        float mean = has ? base[r] + mean_q : 0.f;
        float vmn = has ? base[r] + mn[r] : 0.f;
        float vmx = has ? base[r] + mx[r] : 0.f;
        int f = f0 + r;
        int t = f / F, o = f - t * F;
        size_t rowb = (size_t)n * (4 * TF) + (size_t)t * (4 * F);
        ushort_t h_, l_;
        splitbf(mean, h_, l_); agg_hi[rowb + o] = h_;         agg_lo[rowb + o] = l_;
        splitbf(vmn,  h_, l_); agg_hi[rowb + F + o] = h_;     agg_lo[rowb + F + o] = l_;
        splitbf(vmx,  h_, l_); agg_hi[rowb + 2 * F + o] = h_; agg_lo[rowb + 2 * F + o] = l_;
        splitbf(stdv, h_, l_); agg_hi[rowb + 3 * F + o] = h_; agg_lo[rowb + 3 * F + o] = l_;
    }
    if (lane == 0) {
        float logd = logf(d + 1.f);
        sc[n] = make_float2(logd / kAVG_LOG, kAVG_LOG / logd);
    }
}

// MFMA split-bf16 merged Z+final GEMM, single K-pass (hi/lo tiles co-resident).
// Block tile 64x192, 4 waves; wave = 16 rows x 192 cols (12 16x16 frags).
template <int F, bool POOL>
__global__ __launch_bounds__(256) void gemm_zf(
    const ushort_t* __restrict__ xs_hi, const ushort_t* __restrict__ xs_lo,
    const ushort_t* __restrict__ agg_hi, const ushort_t* __restrict__ agg_lo,
    const ushort_t* __restrict__ Bh, const ushort_t* __restrict__ Bl,
    const float* __restrict__ bias_zf, const float2* __restrict__ sc,
    float* __restrict__ H, ushort_t* __restrict__ H_hi, ushort_t* __restrict__ H_lo,
    const int* __restrict__ batch, float* __restrict__ pool) {
    const int KT = 9 * F;
    extern __shared__ char smem[];
    ushort_t* Ah_s = (ushort_t*)smem;        // [64][40]
    ushort_t* Al_s = Ah_s + 64 * 40;         // [64][40]
    ushort_t* Bh_s = Al_s + 64 * 40;         // [192][40]
    ushort_t* Bl_s = Bh_s + 192 * 40;        // [192][40]
    float* hbuf = (float*)smem;              // POOL alias [64][68]

    int m0 = blockIdx.x * 64;
    int tid = threadIdx.x;
    int lane = tid & 63;
    int wave = tid >> 6;
    int ln = lane & 15, quad = lane >> 4;
    int wrow = wave * 16;

    floatx4 acc[12];
#pragma unroll
    for (int i = 0; i < 12; ++i) acc[i] = (floatx4)(0.f);

    int arow = tid >> 2, asg = tid & 3;
    int agm = m0 + arow;

    for (int k0 = 0; k0 < KT; k0 += 32) {
        {
            int c0 = k0 + asg * 8;
            short8 vh = {0, 0, 0, 0, 0, 0, 0, 0};
            short8 vl = {0, 0, 0, 0, 0, 0, 0, 0};
            if (agm < NN) {
                if (c0 < F) {
                    vh = *(const short8*)(xs_hi + (size_t)agm * F + c0);
                    vl = *(const short8*)(xs_lo + (size_t)agm * F + c0);
                } else {
                    vh = *(const short8*)(agg_hi + (size_t)agm * 8 * F + (c0 - F));
                    vl = *(const short8*)(agg_lo + (size_t)agm * 8 * F + (c0 - F));
                }
            }
            *(short8*)&Ah_s[arow * 40 + asg * 8] = vh;
            *(short8*)&Al_s[arow * 40 + asg * 8] = vl;
        }
#pragma unroll
        for (int p = 0; p < 3; ++p) {
            int idx = tid + 256 * p;
            int col = idx >> 2, sg = idx & 3;
            *(short8*)&Bh_s[col * 40 + sg * 8] = *(const short8*)(Bh + (size_t)col * KT + k0 + sg * 8);
            *(short8*)&Bl_s[col * 40 + sg * 8] = *(const short8*)(Bl + (size_t)col * KT + k0 + sg * 8);
        }
        __syncthreads();
        short8 ah = *(short8*)&Ah_s[(wrow + ln) * 40 + quad * 8];
        short8 al = *(short8*)&Al_s[(wrow + ln) * 40 + quad * 8];
#pragma unroll
        for (int nt = 0; nt < 12; ++nt) {
            short8 bh = *(short8*)&Bh_s[(nt * 16 + ln) * 40 + quad * 8];
            short8 bl = *(short8*)&Bl_s[(nt * 16 + ln) * 40 + quad * 8];
            acc[nt] = __builtin_amdgcn_mfma_f32_16x16x32_bf16(ah, bh, acc[nt], 0, 0, 0);
            acc[nt] = __builtin_amdgcn_mfma_f32_16x16x32_bf16(ah, bl, acc[nt], 0, 0, 0);
            acc[nt] = __builtin_amdgcn_mfma_f32_16x16x32_bf16(al, bh, acc[nt], 0, 0, 0);
        }
        __syncthreads();
    }

    float bj[4];
#pragma unroll
    for (int j = 0; j < 4; ++j) bj[j] = bias_zf[j * 16 + ln];

    if (POOL) __syncthreads();  // smem reuse as hbuf

#pragma unroll
    for (int reg = 0; reg < 4; ++reg) {
        int r = wrow + quad * 4 + reg;
        int gm = m0 + r;
        float2 s = make_float2(0.f, 0.f);
        if (gm < NN) s = sc[gm];
#pragma unroll
        for (int j = 0; j < 4; ++j) {
            float y = acc[j][reg] + s.x * acc[j + 4][reg] + s.y * acc[j + 8][reg] + bj[j];
            y = fmaxf(y, 0.f);
            int col = j * 16 + ln;
            if (POOL) {
                hbuf[r * 68 + col] = (gm < NN) ? y : 0.f;
            } else if (gm < NN) {
                H[(size_t)gm * 64 + col] = y;
                ushort_t h_, l_;
                splitbf(y, h_, l_);
                H_hi[(size_t)gm * 64 + col] = h_;
                H_lo[(size_t)gm * 64 + col] = l_;
            }
        }
    }
    if (POOL) {
        __syncthreads();
        int col = tid & 63, grp = tid >> 6;
        float a = 0.f;
        int cur = -1;
        for (int i = 0; i < 16; ++i) {
            int r = grp * 16 + i;
            int gm = m0 + r;
            if (gm >= NN) break;
            int b = batch[gm];
            if (b != cur) {
                if (cur >= 0) atomicAdd(&pool[cur * 64 + col], a);
                cur = b; a = 0.f;
            }
            a += hbuf[r * 68 + col];
        }
        if (cur >= 0) atomicAdd(&pool[cur * 64 + col], a);
    }
}

__global__ __launch_bounds__(256) void head_kernel(const float* __restrict__ gpool, const float* __restrict__ hls,
                                                   const float* __restrict__ W1, const float* __restrict__ b1,
                                                   const float* __restrict__ W2, const float* __restrict__ b2,
                                                   const float* __restrict__ W3, const float* __restrict__ b3,
                                                   float* __restrict__ out) {
    __shared__ float gin[64][96];
    __shared__ float r1[64][64];
    __shared__ float r2[64][64];
    int tid = threadIdx.x;
    for (int idx = tid; idx < 64 * 96; idx += 256) {
        int g = idx / 96, j = idx % 96;
        gin[g][j] = (j < 64) ? gpool[g * 64 + j] : hls[g * 32 + (j - 64)];
    }
    __syncthreads();
    for (int idx = tid; idx < 64 * 64; idx += 256) {
        int g = idx / 64, j = idx % 64;
        float acc = b1[j];
        for (int k = 0; k < 96; ++k) acc = fmaf(gin[g][k], W1[k * 64 + j], acc);
        r1[g][j] = fmaxf(acc, 0.f);
    }
    __syncthreads();
    for (int idx = tid; idx < 64 * 64; idx += 256) {
        int g = idx / 64, j = idx % 64;
        float acc = b2[j];
        for (int k = 0; k < 64; ++k) acc = fmaf(r1[g][k], W2[k * 64 + j], acc);
        r2[g][j] = fmaxf(acc, 0.f);
    }
    __syncthreads();
    if (tid < 64) {
        float acc = b3[0];
        for (int k = 0; k < 64; ++k) acc = fmaf(r2[tid][k], W3[k], acc);
        out[tid] = acc;
    }
}

extern "C" void kernel_launch(void* const* d_in, const int* in_sizes, int n_in,
                              void* d_out, int out_size, void* d_ws, size_t ws_size,
                              hipStream_t stream) {
    (void)in_sizes; (void)n_in; (void)out_size; (void)ws_size;
    const float* x     = (const float*)d_in[0];
    const float* eattr = (const float*)d_in[1];
    const float* hls   = (const float*)d_in[2];
    const int*   eidx  = (const int*)d_in[3];
    const int*   batch = (const int*)d_in[4];
    const float* We[2]    = {(const float*)d_in[5],  (const float*)d_in[13]};
    const float* be[2]    = {(const float*)d_in[6],  (const float*)d_in[14]};
    const float* Wpre[2]  = {(const float*)d_in[7],  (const float*)d_in[15]};
    const float* bpre[2]  = {(const float*)d_in[8],  (const float*)d_in[16]};
    const float* Wpost[2] = {(const float*)d_in[9],  (const float*)d_in[17]};
    const float* bpost[2] = {(const float*)d_in[10], (const float*)d_in[18]};
    const float* Wlin[2]  = {(const float*)d_in[11], (const float*)d_in[19]};
    const float* blin[2]  = {(const float*)d_in[12], (const float*)d_in[20]};
    const float* W1 = (const float*)d_in[21]; const float* b1 = (const float*)d_in[22];
    const float* W2 = (const float*)d_in[23]; const float* b2 = (const float*)d_in[24];
    const float* W3 = (const float*)d_in[25]; const float* b3 = (const float*)d_in[26];
    float* out = (float*)d_out;

    char* ws = (char*)d_ws;
    size_t off = 0;
    auto carve = [&](size_t bytes) -> char* {
        char* p = ws + off;
        off = (off + bytes + 255) & ~(size_t)255;
        return p;
    };
    int*      cnt     = (int*)carve((size_t)NN * 4);
    int*      csr_src = (int*)carve((size_t)NN * CAP * 4);
    float2*   csr_ea  = (float2*)carve((size_t)NN * CAP * 8);
    float*    ABa     = (float*)carve((size_t)NN * 128 * 4);      // fp32 dst-projection (<=128)
    ushort_t* ABb     = (ushort_t*)carve((size_t)NN * 128 * 2);   // bf16 src-projection (<=128)
    ushort_t* agg_hi  = (ushort_t*)carve((size_t)NN * 512 * 2);
    ushort_t* agg_lo  = (ushort_t*)carve((size_t)NN * 512 * 2);
    float2*   sc      = (float2*)carve((size_t)NN * 8);
    ushort_t* xs_hi   = (ushort_t*)carve((size_t)NN * 32 * 2);
    ushort_t* xs_lo   = (ushort_t*)carve((size_t)NN * 32 * 2);
    float*    h1      = (float*)carve((size_t)NN * 64 * 4);
    ushort_t* h1_hi   = (ushort_t*)carve((size_t)NN * 64 * 2);
    ushort_t* h1_lo   = (ushort_t*)carve((size_t)NN * 64 * 2);
    float*    U       = (float*)carve(256 * 4);
    float*    Wab     = (float*)carve(16384 * 4);
    float*    bias_ab = (float*)carve(256 * 4);
    ushort_t* Bh      = (ushort_t*)carve((size_t)192 * 576 * 2);
    ushort_t* Bl      = (ushort_t*)carve((size_t)192 * 576 * 2);
    float*    bias_zf = (float*)carve(64 * 4);
    float*    pool    = (float*)carve(64 * 64 * 4);

    const int MB128 = (NN + 127) / 128;  // 391
    const int MB64  = (NN + 63) / 64;    // 782
    const int SMEM_ZF = (64 * 40 + 64 * 40 + 192 * 40 + 192 * 40) * 2;  // 40960

    zero_init<<<(NN + 255) / 256, 256, 0, stream>>>(cnt, pool);
    build_csr<<<(EE + 255) / 256, 256, 0, stream>>>(eidx, eattr, cnt, csr_src, csr_ea);
    split_x<<<(NN * 32 + 255) / 256, 256, 0, stream>>>(x, xs_hi, xs_lo, NN * 32);

    // ---------------- layer 0 (F=32, TF=64, KT=288) ----------------
    prep_ab<32><<<1, 256, 0, stream>>>(We[0], be[0], Wpre[0], bpre[0], U, Wab, bias_ab);
    prep_zf<32><<<12, 256, 0, stream>>>(Wpost[0], Wlin[0], bpost[0], blin[0], Bh, Bl, bias_zf);
    gemm_bias<<<dim3(MB128, 2), 256, 0, stream>>>(x, Wab, bias_ab, ABa, ABb, NN, 32, 128, 64);
    aggregate<32><<<(NN + 3) / 4, 256, 0, stream>>>(ABa, ABb, cnt, csr_src, csr_ea, U, agg_hi, agg_lo, sc);
    gemm_zf<32, false><<<MB64, 256, SMEM_ZF, stream>>>(xs_hi, xs_lo, agg_hi, agg_lo, Bh, Bl,
                                                       bias_zf, sc, h1, h1_hi, h1_lo, batch, pool);

    // ---------------- layer 1 (F=64, TF=128, KT=576) ----------------
    prep_ab<64><<<1, 256, 0, stream>>>(We[1], be[1], Wpre[1], bpre[1], U, Wab, bias_ab);
    prep_zf<64><<<12, 256, 0, stream>>>(Wpost[1], Wlin[1], bpost[1], blin[1], Bh, Bl, bias_zf);
    gemm_bias<<<dim3(MB128, 4), 256, 0, stream>>>(h1, Wab, bias_ab, ABa, ABb, NN, 64, 256, 128);
    aggregate<64><<<(NN + 3) / 4, 256, 0, stream>>>(ABa, ABb, cnt, csr_src, csr_ea, U, agg_hi, agg_lo, sc);
    gemm_zf<64, true><<<MB64, 256, SMEM_ZF, stream>>>(h1_hi, h1_lo, agg_hi, agg_lo, Bh, Bl,
                                                      bias_zf, sc, nullptr, nullptr, nullptr, batch, pool);

    // ---------------- head ----------------
    head_kernel<<<1, 256, 0, stream>>>(pool, hls, W1, b1, W2, b2, W3, b3, out);
}

// Round 7
// 527.209 us; speedup vs baseline: 1.1013x; 1.0117x over previous
//
#include <hip/hip_runtime.h>
#include <math.h>
#include <float.h>

// Problem constants (HierNet_55705725829422)
#define NN 50000      // nodes
#define EE 800000     // edges
#define CAP 64        // max in-degree capacity (Poisson(16): P(>=64) ~ 1e-19)

typedef unsigned short ushort_t;
typedef short short8 __attribute__((ext_vector_type(8)));
typedef float floatx4 __attribute__((ext_vector_type(4)));

__device__ __constant__ float kAVG_LOG = 2.8332133440562162f; // log(17)

__device__ inline ushort_t f2bf(float v) {
    union { float f; unsigned u; } x; x.f = v;
    unsigned r = x.u + 0x7fffu + ((x.u >> 16) & 1u);
    return (ushort_t)(r >> 16);
}
__device__ inline float bf2f(ushort_t b) {
    union { unsigned u; float f; } x; x.u = ((unsigned)b) << 16; return x.f;
}
__device__ inline float bitsf(unsigned u) {
    union { unsigned u; float f; } x; x.u = u; return x.f;
}
__device__ inline void splitbf(float v, ushort_t& hi, ushort_t& lo) {
    hi = f2bf(v);
    lo = f2bf(v - bf2f(hi));
}

__global__ __launch_bounds__(256) void zero_init(int* cnt, float* pool) {
    int i = blockIdx.x * 256 + threadIdx.x;
    if (i < NN) cnt[i] = 0;
    if (i < 64 * 64) pool[i] = 0.f;
}

__global__ __launch_bounds__(256) void build_csr(const int* __restrict__ ei, const float* __restrict__ ea,
                                                 int* __restrict__ cnt, int* __restrict__ csr_src,
                                                 float2* __restrict__ csr_ea) {
    int e = blockIdx.x * 256 + threadIdx.x;
    if (e >= EE) return;
    int s = ei[e];
    int d = ei[EE + e];
    float2 v = *(const float2*)(ea + 2 * e);
    int p = atomicAdd(&cnt[d], 1);
    if (p < CAP) {
        csr_src[d * CAP + p] = s;
        csr_ea[d * CAP + p] = v;
    }
}

__global__ __launch_bounds__(256) void split_x(const float* __restrict__ x, ushort_t* __restrict__ hi,
                                               ushort_t* __restrict__ lo, int n) {
    int i = blockIdx.x * 256 + threadIdx.x;
    if (i < n) splitbf(x[i], hi[i], lo[i]);
}

// per-layer A/B-projection weight prep: U, Wab (fp32), bias_ab
template <int F>
__global__ __launch_bounds__(256) void prep_ab(const float* __restrict__ We, const float* __restrict__ be,
                                               const float* __restrict__ Wpre, const float* __restrict__ bpre,
                                               float* __restrict__ U, float* __restrict__ Wab,
                                               float* __restrict__ bias_ab) {
    const int TF = 2 * F;
    int tid = threadIdx.x;
    for (int idx = tid; idx < 2 * TF; idx += 256) {
        int c = idx / TF, f = idx % TF;
        int t = f / F, o = f % F;
        float s = 0.f;
        for (int g = 0; g < F; ++g)
            s += We[c * F + g] * Wpre[((size_t)t * 3 * F + 2 * F + g) * F + o];
        U[idx] = s;
    }
    for (int idx = tid; idx < F * 2 * TF; idx += 256) {
        int g = idx / (2 * TF), cc = idx % (2 * TF);
        int t, o, row;
        if (cc < TF) { t = cc / F; o = cc % F; row = g; }
        else { int c2 = cc - TF; t = c2 / F; o = c2 % F; row = F + g; }
        Wab[idx] = Wpre[((size_t)t * 3 * F + row) * F + o];
    }
    for (int cc = tid; cc < 2 * TF; cc += 256) {
        float v = 0.f;
        if (cc < TF) {
            int t = cc / F, o = cc % F;
            float s = 0.f;
            for (int g = 0; g < F; ++g)
                s += be[g] * Wpre[((size_t)t * 3 * F + 2 * F + g) * F + o];
            v = s + bpre[t * F + o];
        }
        bias_ab[cc] = v;
    }
}

// Folded Z/final weights, split to bf16 hi/lo, stored COL-MAJOR [192 cols][KT]
template <int F>
__global__ __launch_bounds__(256) void prep_zf(const float* __restrict__ Wpost, const float* __restrict__ Wlin,
                                               const float* __restrict__ bpost, const float* __restrict__ blin,
                                               ushort_t* __restrict__ Bh, ushort_t* __restrict__ Bl,
                                               float* __restrict__ bias_zf) {
    const int KT = 9 * F;
    int bx = blockIdx.x;  // 12 blocks x 16 cols
    int tid = threadIdx.x;
    for (int idx = tid; idx < 16 * KT; idx += 256) {
        int jj = idx / KT, k = idx % KT;
        int jg = bx * 16 + jj;
        int b = jg >> 6, j = jg & 63;
        float v = 0.f;
        if (k < F) {
            if (b == 0) {
                float s = 0.f;
                for (int t = 0; t < 2; ++t)
                    for (int c = 0; c < 32; ++c)
                        s += Wpost[((size_t)t * 13 * F + k) * 32 + c] * Wlin[(t * 32 + c) * 64 + j];
                v = s;
            }
        } else {
            int r = k - F;
            int t = r / (4 * F), rr = r - t * 4 * F;
            float s = 0.f;
            for (int c = 0; c < 32; ++c)
                s += Wpost[((size_t)t * 13 * F + F + b * 4 * F + rr) * 32 + c] * Wlin[(t * 32 + c) * 64 + j];
            v = s;
        }
        ushort_t h_, l_;
        splitbf(v, h_, l_);
        Bh[(size_t)jg * KT + k] = h_;
        Bl[(size_t)jg * KT + k] = l_;
    }
    if (bx == 0) {
        for (int j = tid; j < 64; j += 256) {
            float s = blin[j];
            for (int t = 0; t < 2; ++t)
                for (int c = 0; c < 32; ++c)
                    s += bpost[t * 32 + c] * Wlin[(t * 32 + c) * 64 + j];
            bias_zf[j] = s;
        }
    }
}

// fp32 GEMM: [Ca | Cb] = A[MxK]@B[KxN] + bias. Columns < bstart -> fp32 Ca; >= bstart -> bf16 Cb.
// Tile 128x64, micro 8x4. bstart multiple of 64.
__global__ __launch_bounds__(256) void gemm_bias(const float* __restrict__ A, const float* __restrict__ B,
                                                 const float* __restrict__ bias, float* __restrict__ Ca,
                                                 ushort_t* __restrict__ Cb, int M, int K, int Ncols, int bstart) {
    __shared__ float As[32][132];
    __shared__ float Bs[32][68];
    int m0 = blockIdx.x * 128, c0 = blockIdx.y * 64;
    int tid = threadIdx.x;
    int tx = tid & 15, ty = tid >> 4;
    int ms = tid >> 3, u = tid & 7;
    float acc[8][4] = {};
    for (int k0 = 0; k0 < K; k0 += 32) {
#pragma unroll
        for (int p = 0; p < 4; ++p) {
            int m = ms + 32 * p;
            int gm = m0 + m;
            float4 v = make_float4(0.f, 0.f, 0.f, 0.f);
            if (gm < M) v = *(const float4*)(A + (size_t)gm * K + k0 + u * 4);
            As[u * 4 + 0][m] = v.x; As[u * 4 + 1][m] = v.y;
            As[u * 4 + 2][m] = v.z; As[u * 4 + 3][m] = v.w;
        }
#pragma unroll
        for (int p = 0; p < 2; ++p) {
            int idx = tid + 256 * p;
            int kk = idx >> 4, q = idx & 15;
            *(float4*)&Bs[kk][q * 4] = *(const float4*)(B + (size_t)(k0 + kk) * Ncols + c0 + q * 4);
        }
        __syncthreads();
#pragma unroll 8
        for (int k = 0; k < 32; ++k) {
            float a0[8], b0[4];
            *(float4*)&a0[0] = *(const float4*)&As[k][ty * 8];
            *(float4*)&a0[4] = *(const float4*)&As[k][ty * 8 + 4];
            *(float4*)&b0[0] = *(const float4*)&Bs[k][tx * 4];
#pragma unroll
            for (int i = 0; i < 8; ++i)
#pragma unroll
                for (int j = 0; j < 4; ++j) acc[i][j] = fmaf(a0[i], b0[j], acc[i][j]);
        }
        __syncthreads();
    }
    float bj[4];
#pragma unroll
    for (int j = 0; j < 4; ++j) bj[j] = bias[c0 + tx * 4 + j];
    bool bside = (c0 >= bstart);
    int TFw = bstart;  // row stride of both halves
#pragma unroll
    for (int i = 0; i < 8; ++i) {
        int gm = m0 + ty * 8 + i;
        if (gm >= M) continue;
        float v0 = acc[i][0] + bj[0], v1 = acc[i][1] + bj[1];
        float v2 = acc[i][2] + bj[2], v3 = acc[i][3] + bj[3];
        if (!bside) {
            *(float4*)(Ca + (size_t)gm * TFw + c0 + tx * 4) = make_float4(v0, v1, v2, v3);
        } else {
            ushort4 w;
            w.x = f2bf(v0); w.y = f2bf(v1); w.z = f2bf(v2); w.w = f2bf(v3);
            *(ushort4*)(Cb + (size_t)gm * TFw + (c0 - bstart) + tx * 4) = w;
        }
    }
}

// aggregate: ONE wave per node (FPL = TF/64 features per lane, bf16 gather).
template <int F>
__global__ __launch_bounds__(256) void aggregate(const float* __restrict__ ABa, const ushort_t* __restrict__ ABb,
                                                 const int* __restrict__ cnt, const int* __restrict__ csr_src,
                                                 const float2* __restrict__ csr_ea, const float* __restrict__ U,
                                                 ushort_t* __restrict__ agg_hi, ushort_t* __restrict__ agg_lo,
                                                 float2* __restrict__ sc) {
    const int TF = 2 * F;
    const int FPL = TF / 64;  // 1 (F=32) or 2 (F=64)
    int lane = threadIdx.x & 63;
    int n = blockIdx.x * 4 + (threadIdx.x >> 6);
    if (n >= NN) return;
    int f0 = FPL * lane;

    float base[FPL], u0[FPL], u1[FPL], sum[FPL], sq[FPL], mn[FPL], mx[FPL];
#pragma unroll
    for (int r = 0; r < FPL; ++r) {
        base[r] = ABa[(size_t)n * TF + f0 + r];
        u0[r] = U[f0 + r];
        u1[r] = U[TF + f0 + r];
        sum[r] = 0.f; sq[r] = 0.f; mn[r] = FLT_MAX; mx[r] = -FLT_MAX;
    }
    int deg = cnt[n];
    int ec = deg < CAP ? deg : CAP;
    if (ec > 0) {
        int ebase = n * CAP;
        int myi = lane < ec ? lane : ec - 1;
        int msrc = csr_src[ebase + myi];
        float2 mea = csr_ea[ebase + myi];
        for (int e = 0; e < ec; e += 8) {
            int sb[8]; float ex[8], ey[8];
            unsigned wv[8];
#pragma unroll
            for (int i = 0; i < 8; ++i) {
                sb[i] = __shfl(msrc, e + i);
                ex[i] = __shfl(mea.x, e + i);
                ey[i] = __shfl(mea.y, e + i);
            }
#pragma unroll
            for (int i = 0; i < 8; ++i) {
                if (e + i < ec) {
                    if (FPL == 2)
                        wv[i] = *(const unsigned*)(ABb + (size_t)sb[i] * TF + f0);
                    else
                        wv[i] = ABb[(size_t)sb[i] * TF + f0];
                }
            }
#pragma unroll
            for (int i = 0; i < 8; ++i) {
                if (e + i < ec) {
                    float v[FPL];
                    if (FPL == 2) {
                        v[0] = bitsf(wv[i] << 16);
                        v[1] = bitsf(wv[i] & 0xffff0000u);
                    } else {
                        v[0] = bitsf(wv[i] << 16);
                    }
#pragma unroll
                    for (int r = 0; r < FPL; ++r) {
                        float q = fmaf(ex[i], u0[r], fmaf(ey[i], u1[r], v[r]));
                        sum[r] += q;
                        sq[r] = fmaf(q, q, sq[r]);
                        mn[r] = fminf(mn[r], q);
                        mx[r] = fmaxf(mx[r], q);
                    }
                }
            }
        }
    }
    float d = (float)(deg > 1 ? deg : 1);
    float inv_d = 1.f / d;
    bool has = deg > 0;
#pragma unroll
    for (int r = 0; r < FPL; ++r) {
        float mean_q = sum[r] * inv_d;
        float var = sq[r] * inv_d - mean_q * mean_q;
        float stdv = sqrtf(fmaxf(var, 0.f) + 1e-5f);
        float mean = has ? base[r] + mean_q : 0.f;
        float vmn = has ? base[r] + mn[r] : 0.f;
        float vmx = has ? base[r] + mx[r] : 0.f;
        int f = f0 + r;
        int t = f / F, o = f - t * F;
        size_t rowb = (size_t)n * (4 * TF) + (size_t)t * (4 * F);
        ushort_t h_, l_;
        splitbf(mean, h_, l_); agg_hi[rowb + o] = h_;         agg_lo[rowb + o] = l_;
        splitbf(vmn,  h_, l_); agg_hi[rowb + F + o] = h_;     agg_lo[rowb + F + o] = l_;
        splitbf(vmx,  h_, l_); agg_hi[rowb + 2 * F + o] = h_; agg_lo[rowb + 2 * F + o] = l_;
        splitbf(stdv, h_, l_); agg_hi[rowb + 3 * F + o] = h_; agg_lo[rowb + 3 * F + o] = l_;
    }
    if (lane == 0) {
        float logd = logf(d + 1.f);
        sc[n] = make_float2(logd / kAVG_LOG, kAVG_LOG / logd);
    }
}

// MFMA split-bf16 merged Z+final GEMM, single K-pass.
// NEW wave tiling: block 64 rows x 192 cols; wave w owns col-frags {w, w+4, w+8}
// (16 cols in each scaler block) x all 4 row-frags. Per k0: 8 A reads + 6 B reads, 36 MFMA.
template <int F, bool POOL>
__global__ __launch_bounds__(256) void gemm_zf(
    const ushort_t* __restrict__ xs_hi, const ushort_t* __restrict__ xs_lo,
    const ushort_t* __restrict__ agg_hi, const ushort_t* __restrict__ agg_lo,
    const ushort_t* __restrict__ Bh, const ushort_t* __restrict__ Bl,
    const float* __restrict__ bias_zf, const float2* __restrict__ sc,
    float* __restrict__ H, ushort_t* __restrict__ H_hi, ushort_t* __restrict__ H_lo,
    const int* __restrict__ batch, float* __restrict__ pool) {
    const int KT = 9 * F;
    extern __shared__ char smem[];
    ushort_t* Ah_s = (ushort_t*)smem;        // [64][40]
    ushort_t* Al_s = Ah_s + 64 * 40;         // [64][40]
    ushort_t* Bh_s = Al_s + 64 * 40;         // [192][40]
    ushort_t* Bl_s = Bh_s + 192 * 40;        // [192][40]
    float* hbuf = (float*)smem;              // POOL alias [64][68]

    int m0 = blockIdx.x * 64;
    int tid = threadIdx.x;
    int lane = tid & 63;
    int wave = tid >> 6;
    int ln = lane & 15, quad = lane >> 4;

    floatx4 acc[4][3];
#pragma unroll
    for (int i = 0; i < 4; ++i)
#pragma unroll
        for (int j = 0; j < 3; ++j) acc[i][j] = (floatx4)(0.f);

    int arow = tid >> 2, asg = tid & 3;
    int agm = m0 + arow;

    for (int k0 = 0; k0 < KT; k0 += 32) {
        {
            int c0 = k0 + asg * 8;
            short8 vh = {0, 0, 0, 0, 0, 0, 0, 0};
            short8 vl = {0, 0, 0, 0, 0, 0, 0, 0};
            if (agm < NN) {
                if (c0 < F) {
                    vh = *(const short8*)(xs_hi + (size_t)agm * F + c0);
                    vl = *(const short8*)(xs_lo + (size_t)agm * F + c0);
                } else {
                    vh = *(const short8*)(agg_hi + (size_t)agm * 8 * F + (c0 - F));
                    vl = *(const short8*)(agg_lo + (size_t)agm * 8 * F + (c0 - F));
                }
            }
            *(short8*)&Ah_s[arow * 40 + asg * 8] = vh;
            *(short8*)&Al_s[arow * 40 + asg * 8] = vl;
        }
#pragma unroll
        for (int p = 0; p < 3; ++p) {
            int idx = tid + 256 * p;
            int col = idx >> 2, sg = idx & 3;
            *(short8*)&Bh_s[col * 40 + sg * 8] = *(const short8*)(Bh + (size_t)col * KT + k0 + sg * 8);
            *(short8*)&Bl_s[col * 40 + sg * 8] = *(const short8*)(Bl + (size_t)col * KT + k0 + sg * 8);
        }
        __syncthreads();
        short8 ah[4], al[4], bh[3], bl[3];
#pragma unroll
        for (int rf = 0; rf < 4; ++rf) {
            ah[rf] = *(short8*)&Ah_s[(rf * 16 + ln) * 40 + quad * 8];
            al[rf] = *(short8*)&Al_s[(rf * 16 + ln) * 40 + quad * 8];
        }
#pragma unroll
        for (int b = 0; b < 3; ++b) {
            int col = b * 64 + wave * 16 + ln;
            bh[b] = *(short8*)&Bh_s[col * 40 + quad * 8];
            bl[b] = *(short8*)&Bl_s[col * 40 + quad * 8];
        }
#pragma unroll
        for (int rf = 0; rf < 4; ++rf)
#pragma unroll
            for (int b = 0; b < 3; ++b) {
                acc[rf][b] = __builtin_amdgcn_mfma_f32_16x16x32_bf16(ah[rf], bh[b], acc[rf][b], 0, 0, 0);
                acc[rf][b] = __builtin_amdgcn_mfma_f32_16x16x32_bf16(ah[rf], bl[b], acc[rf][b], 0, 0, 0);
                acc[rf][b] = __builtin_amdgcn_mfma_f32_16x16x32_bf16(al[rf], bh[b], acc[rf][b], 0, 0, 0);
            }
        __syncthreads();
    }

    int ocol = wave * 16 + ln;  // output col 0..63
    float bcol = bias_zf[ocol];

#pragma unroll
    for (int rf = 0; rf < 4; ++rf) {
#pragma unroll
        for (int reg = 0; reg < 4; ++reg) {
            int r = rf * 16 + quad * 4 + reg;
            int gm = m0 + r;
            float2 s = make_float2(0.f, 0.f);
            if (gm < NN) s = sc[gm];
            float y = acc[rf][0][reg] + s.x * acc[rf][1][reg] + s.y * acc[rf][2][reg] + bcol;
            y = fmaxf(y, 0.f);
            if (POOL) {
                hbuf[r * 68 + ocol] = (gm < NN) ? y : 0.f;
            } else if (gm < NN) {
                H[(size_t)gm * 64 + ocol] = y;
                ushort_t h_, l_;
                splitbf(y, h_, l_);
                H_hi[(size_t)gm * 64 + ocol] = h_;
                H_lo[(size_t)gm * 64 + ocol] = l_;
            }
        }
    }
    if (POOL) {
        __syncthreads();
        int col = tid & 63, grp = tid >> 6;
        float a = 0.f;
        int cur = -1;
        for (int i = 0; i < 16; ++i) {
            int r = grp * 16 + i;
            int gm = m0 + r;
            if (gm >= NN) break;
            int b = batch[gm];
            if (b != cur) {
                if (cur >= 0) atomicAdd(&pool[cur * 64 + col], a);
                cur = b; a = 0.f;
            }
            a += hbuf[r * 68 + col];
        }
        if (cur >= 0) atomicAdd(&pool[cur * 64 + col], a);
    }
}

__global__ __launch_bounds__(256) void head_kernel(const float* __restrict__ gpool, const float* __restrict__ hls,
                                                   const float* __restrict__ W1, const float* __restrict__ b1,
                                                   const float* __restrict__ W2, const float* __restrict__ b2,
                                                   const float* __restrict__ W3, const float* __restrict__ b3,
                                                   float* __restrict__ out) {
    __shared__ float gin[64][96];
    __shared__ float r1[64][64];
    __shared__ float r2[64][64];
    int tid = threadIdx.x;
    for (int idx = tid; idx < 64 * 96; idx += 256) {
        int g = idx / 96, j = idx % 96;
        gin[g][j] = (j < 64) ? gpool[g * 64 + j] : hls[g * 32 + (j - 64)];
    }
    __syncthreads();
    for (int idx = tid; idx < 64 * 64; idx += 256) {
        int g = idx / 64, j = idx % 64;
        float acc = b1[j];
        for (int k = 0; k < 96; ++k) acc = fmaf(gin[g][k], W1[k * 64 + j], acc);
        r1[g][j] = fmaxf(acc, 0.f);
    }
    __syncthreads();
    for (int idx = tid; idx < 64 * 64; idx += 256) {
        int g = idx / 64, j = idx % 64;
        float acc = b2[j];
        for (int k = 0; k < 64; ++k) acc = fmaf(r1[g][k], W2[k * 64 + j], acc);
        r2[g][j] = fmaxf(acc, 0.f);
    }
    __syncthreads();
    if (tid < 64) {
        float acc = b3[0];
        for (int k = 0; k < 64; ++k) acc = fmaf(r2[tid][k], W3[k], acc);
        out[tid] = acc;
    }
}

extern "C" void kernel_launch(void* const* d_in, const int* in_sizes, int n_in,
                              void* d_out, int out_size, void* d_ws, size_t ws_size,
                              hipStream_t stream) {
    (void)in_sizes; (void)n_in; (void)out_size; (void)ws_size;
    const float* x     = (const float*)d_in[0];
    const float* eattr = (const float*)d_in[1];
    const float* hls   = (const float*)d_in[2];
    const int*   eidx  = (const int*)d_in[3];
    const int*   batch = (const int*)d_in[4];
    const float* We[2]    = {(const float*)d_in[5],  (const float*)d_in[13]};
    const float* be[2]    = {(const float*)d_in[6],  (const float*)d_in[14]};
    const float* Wpre[2]  = {(const float*)d_in[7],  (const float*)d_in[15]};
    const float* bpre[2]  = {(const float*)d_in[8],  (const float*)d_in[16]};
    const float* Wpost[2] = {(const float*)d_in[9],  (const float*)d_in[17]};
    const float* bpost[2] = {(const float*)d_in[10], (const float*)d_in[18]};
    const float* Wlin[2]  = {(const float*)d_in[11], (const float*)d_in[19]};
    const float* blin[2]  = {(const float*)d_in[12], (const float*)d_in[20]};
    const float* W1 = (const float*)d_in[21]; const float* b1 = (const float*)d_in[22];
    const float* W2 = (const float*)d_in[23]; const float* b2 = (const float*)d_in[24];
    const float* W3 = (const float*)d_in[25]; const float* b3 = (const float*)d_in[26];
    float* out = (float*)d_out;

    char* ws = (char*)d_ws;
    size_t off = 0;
    auto carve = [&](size_t bytes) -> char* {
        char* p = ws + off;
        off = (off + bytes + 255) & ~(size_t)255;
        return p;
    };
    int*      cnt     = (int*)carve((size_t)NN * 4);
    int*      csr_src = (int*)carve((size_t)NN * CAP * 4);
    float2*   csr_ea  = (float2*)carve((size_t)NN * CAP * 8);
    float*    ABa     = (float*)carve((size_t)NN * 128 * 4);      // fp32 dst-projection
    ushort_t* ABb     = (ushort_t*)carve((size_t)NN * 128 * 2);   // bf16 src-projection
    ushort_t* agg_hi  = (ushort_t*)carve((size_t)NN * 512 * 2);
    ushort_t* agg_lo  = (ushort_t*)carve((size_t)NN * 512 * 2);
    float2*   sc      = (float2*)carve((size_t)NN * 8);
    ushort_t* xs_hi   = (ushort_t*)carve((size_t)NN * 32 * 2);
    ushort_t* xs_lo   = (ushort_t*)carve((size_t)NN * 32 * 2);
    float*    h1      = (float*)carve((size_t)NN * 64 * 4);
    ushort_t* h1_hi   = (ushort_t*)carve((size_t)NN * 64 * 2);
    ushort_t* h1_lo   = (ushort_t*)carve((size_t)NN * 64 * 2);
    float*    U       = (float*)carve(256 * 4);
    float*    Wab     = (float*)carve(16384 * 4);
    float*    bias_ab = (float*)carve(256 * 4);
    ushort_t* Bh      = (ushort_t*)carve((size_t)192 * 576 * 2);
    ushort_t* Bl      = (ushort_t*)carve((size_t)192 * 576 * 2);
    float*    bias_zf = (float*)carve(64 * 4);
    float*    pool    = (float*)carve(64 * 64 * 4);

    const int MB128 = (NN + 127) / 128;  // 391
    const int MB64  = (NN + 63) / 64;    // 782
    const int SMEM_ZF = (64 * 40 + 64 * 40 + 192 * 40 + 192 * 40) * 2;  // 40960

    zero_init<<<(NN + 255) / 256, 256, 0, stream>>>(cnt, pool);
    build_csr<<<(EE + 255) / 256, 256, 0, stream>>>(eidx, eattr, cnt, csr_src, csr_ea);
    split_x<<<(NN * 32 + 255) / 256, 256, 0, stream>>>(x, xs_hi, xs_lo, NN * 32);

    // ---------------- layer 0 (F=32, TF=64, KT=288) ----------------
    prep_ab<32><<<1, 256, 0, stream>>>(We[0], be[0], Wpre[0], bpre[0], U, Wab, bias_ab);
    prep_zf<32><<<12, 256, 0, stream>>>(Wpost[0], Wlin[0], bpost[0], blin[0], Bh, Bl, bias_zf);
    gemm_bias<<<dim3(MB128, 2), 256, 0, stream>>>(x, Wab, bias_ab, ABa, ABb, NN, 32, 128, 64);
    aggregate<32><<<(NN + 3) / 4, 256, 0, stream>>>(ABa, ABb, cnt, csr_src, csr_ea, U, agg_hi, agg_lo, sc);
    gemm_zf<32, false><<<MB64, 256, SMEM_ZF, stream>>>(xs_hi, xs_lo, agg_hi, agg_lo, Bh, Bl,
                                                       bias_zf, sc, h1, h1_hi, h1_lo, batch, pool);

    // ---------------- layer 1 (F=64, TF=128, KT=576) ----------------
    prep_ab<64><<<1, 256, 0, stream>>>(We[1], be[1], Wpre[1], bpre[1], U, Wab, bias_ab);
    prep_zf<64><<<12, 256, 0, stream>>>(Wpost[1], Wlin[1], bpost[1], blin[1], Bh, Bl, bias_zf);
    gemm_bias<<<dim3(MB128, 4), 256, 0, stream>>>(h1, Wab, bias_ab, ABa, ABb, NN, 64, 256, 128);
    aggregate<64><<<(NN + 3) / 4, 256, 0, stream>>>(ABa, ABb, cnt, csr_src, csr_ea, U, agg_hi, agg_lo, sc);
    gemm_zf<64, true><<<MB64, 256, SMEM_ZF, stream>>>(h1_hi, h1_lo, agg_hi, agg_lo, Bh, Bl,
                                                      bias_zf, sc, nullptr, nullptr, nullptr, batch, pool);

    // ---------------- head ----------------
    head_kernel<<<1, 256, 0, stream>>>(pool, hls, W1, b1, W2, b2, W3, b3, out);
}

// Round 8
// 492.489 us; speedup vs baseline: 1.1789x; 1.0705x over previous
//
#include <hip/hip_runtime.h>
#include <math.h>
#include <float.h>

// Problem constants (HierNet_55705725829422)
#define NN 50000      // nodes
#define EE 800000     // edges
#define CAP 64        // max in-degree capacity (Poisson(16): P(>=64) ~ 1e-19)

typedef unsigned short ushort_t;
typedef short short8 __attribute__((ext_vector_type(8)));
typedef float floatx4 __attribute__((ext_vector_type(4)));

__device__ __constant__ float kAVG_LOG = 2.8332133440562162f; // log(17)

__device__ inline ushort_t f2bf(float v) {
    union { float f; unsigned u; } x; x.f = v;
    unsigned r = x.u + 0x7fffu + ((x.u >> 16) & 1u);
    return (ushort_t)(r >> 16);
}
__device__ inline float bf2f(ushort_t b) {
    union { unsigned u; float f; } x; x.u = ((unsigned)b) << 16; return x.f;
}
__device__ inline float bitsf(unsigned u) {
    union { unsigned u; float f; } x; x.u = u; return x.f;
}
__device__ inline void splitbf(float v, ushort_t& hi, ushort_t& lo) {
    hi = f2bf(v);
    lo = f2bf(v - bf2f(hi));
}

__global__ __launch_bounds__(256) void zero_init(int* cnt, float* pool) {
    int i = blockIdx.x * 256 + threadIdx.x;
    if (i < NN) cnt[i] = 0;
    if (i < 64 * 64) pool[i] = 0.f;
}

__global__ __launch_bounds__(256) void build_csr(const int* __restrict__ ei, const float* __restrict__ ea,
                                                 int* __restrict__ cnt, int* __restrict__ csr_src,
                                                 float2* __restrict__ csr_ea) {
    int e = blockIdx.x * 256 + threadIdx.x;
    if (e >= EE) return;
    int s = ei[e];
    int d = ei[EE + e];
    float2 v = *(const float2*)(ea + 2 * e);
    int p = atomicAdd(&cnt[d], 1);
    if (p < CAP) {
        csr_src[d * CAP + p] = s;
        csr_ea[d * CAP + p] = v;
    }
}

__global__ __launch_bounds__(256) void cast_x(const float* __restrict__ x, ushort_t* __restrict__ xb, int n) {
    int i = blockIdx.x * 256 + threadIdx.x;
    if (i < n) xb[i] = f2bf(x[i]);
}

// per-layer A/B-projection weight prep: U, Wab (fp32), bias_ab
template <int F>
__global__ __launch_bounds__(256) void prep_ab(const float* __restrict__ We, const float* __restrict__ be,
                                               const float* __restrict__ Wpre, const float* __restrict__ bpre,
                                               float* __restrict__ U, float* __restrict__ Wab,
                                               float* __restrict__ bias_ab) {
    const int TF = 2 * F;
    int tid = threadIdx.x;
    for (int idx = tid; idx < 2 * TF; idx += 256) {
        int c = idx / TF, f = idx % TF;
        int t = f / F, o = f % F;
        float s = 0.f;
        for (int g = 0; g < F; ++g)
            s += We[c * F + g] * Wpre[((size_t)t * 3 * F + 2 * F + g) * F + o];
        U[idx] = s;
    }
    for (int idx = tid; idx < F * 2 * TF; idx += 256) {
        int g = idx / (2 * TF), cc = idx % (2 * TF);
        int t, o, row;
        if (cc < TF) { t = cc / F; o = cc % F; row = g; }
        else { int c2 = cc - TF; t = c2 / F; o = c2 % F; row = F + g; }
        Wab[idx] = Wpre[((size_t)t * 3 * F + row) * F + o];
    }
    for (int cc = tid; cc < 2 * TF; cc += 256) {
        float v = 0.f;
        if (cc < TF) {
            int t = cc / F, o = cc % F;
            float s = 0.f;
            for (int g = 0; g < F; ++g)
                s += be[g] * Wpre[((size_t)t * 3 * F + 2 * F + g) * F + o];
            v = s + bpre[t * F + o];
        }
        bias_ab[cc] = v;
    }
}

// Folded Z/final weights, split to bf16 hi/lo, stored COL-MAJOR [192 cols][KT]
template <int F>
__global__ __launch_bounds__(256) void prep_zf(const float* __restrict__ Wpost, const float* __restrict__ Wlin,
                                               const float* __restrict__ bpost, const float* __restrict__ blin,
                                               ushort_t* __restrict__ Bh, ushort_t* __restrict__ Bl,
                                               float* __restrict__ bias_zf) {
    const int KT = 9 * F;
    int bx = blockIdx.x;  // 12 blocks x 16 cols
    int tid = threadIdx.x;
    for (int idx = tid; idx < 16 * KT; idx += 256) {
        int jj = idx / KT, k = idx % KT;
        int jg = bx * 16 + jj;
        int b = jg >> 6, j = jg & 63;
        float v = 0.f;
        if (k < F) {
            if (b == 0) {
                float s = 0.f;
                for (int t = 0; t < 2; ++t)
                    for (int c = 0; c < 32; ++c)
                        s += Wpost[((size_t)t * 13 * F + k) * 32 + c] * Wlin[(t * 32 + c) * 64 + j];
                v = s;
            }
        } else {
            int r = k - F;
            int t = r / (4 * F), rr = r - t * 4 * F;
            float s = 0.f;
            for (int c = 0; c < 32; ++c)
                s += Wpost[((size_t)t * 13 * F + F + b * 4 * F + rr) * 32 + c] * Wlin[(t * 32 + c) * 64 + j];
            v = s;
        }
        ushort_t h_, l_;
        splitbf(v, h_, l_);
        Bh[(size_t)jg * KT + k] = h_;
        Bl[(size_t)jg * KT + k] = l_;
    }
    if (bx == 0) {
        for (int j = tid; j < 64; j += 256) {
            float s = blin[j];
            for (int t = 0; t < 2; ++t)
                for (int c = 0; c < 32; ++c)
                    s += bpost[t * 32 + c] * Wlin[(t * 32 + c) * 64 + j];
            bias_zf[j] = s;
        }
    }
}

// fp32 GEMM: [Ca | Cb] = A[MxK]@B[KxN] + bias. Columns < bstart -> fp32 Ca; >= bstart -> bf16 Cb.
__global__ __launch_bounds__(256) void gemm_bias(const float* __restrict__ A, const float* __restrict__ B,
                                                 const float* __restrict__ bias, float* __restrict__ Ca,
                                                 ushort_t* __restrict__ Cb, int M, int K, int Ncols, int bstart) {
    __shared__ float As[32][132];
    __shared__ float Bs[32][68];
    int m0 = blockIdx.x * 128, c0 = blockIdx.y * 64;
    int tid = threadIdx.x;
    int tx = tid & 15, ty = tid >> 4;
    int ms = tid >> 3, u = tid & 7;
    float acc[8][4] = {};
    for (int k0 = 0; k0 < K; k0 += 32) {
#pragma unroll
        for (int p = 0; p < 4; ++p) {
            int m = ms + 32 * p;
            int gm = m0 + m;
            float4 v = make_float4(0.f, 0.f, 0.f, 0.f);
            if (gm < M) v = *(const float4*)(A + (size_t)gm * K + k0 + u * 4);
            As[u * 4 + 0][m] = v.x; As[u * 4 + 1][m] = v.y;
            As[u * 4 + 2][m] = v.z; As[u * 4 + 3][m] = v.w;
        }
#pragma unroll
        for (int p = 0; p < 2; ++p) {
            int idx = tid + 256 * p;
            int kk = idx >> 4, q = idx & 15;
            *(float4*)&Bs[kk][q * 4] = *(const float4*)(B + (size_t)(k0 + kk) * Ncols + c0 + q * 4);
        }
        __syncthreads();
#pragma unroll 8
        for (int k = 0; k < 32; ++k) {
            float a0[8], b0[4];
            *(float4*)&a0[0] = *(const float4*)&As[k][ty * 8];
            *(float4*)&a0[4] = *(const float4*)&As[k][ty * 8 + 4];
            *(float4*)&b0[0] = *(const float4*)&Bs[k][tx * 4];
#pragma unroll
            for (int i = 0; i < 8; ++i)
#pragma unroll
                for (int j = 0; j < 4; ++j) acc[i][j] = fmaf(a0[i], b0[j], acc[i][j]);
        }
        __syncthreads();
    }
    float bj[4];
#pragma unroll
    for (int j = 0; j < 4; ++j) bj[j] = bias[c0 + tx * 4 + j];
    bool bside = (c0 >= bstart);
    int TFw = bstart;  // row stride of both halves
#pragma unroll
    for (int i = 0; i < 8; ++i) {
        int gm = m0 + ty * 8 + i;
        if (gm >= M) continue;
        float v0 = acc[i][0] + bj[0], v1 = acc[i][1] + bj[1];
        float v2 = acc[i][2] + bj[2], v3 = acc[i][3] + bj[3];
        if (!bside) {
            *(float4*)(Ca + (size_t)gm * TFw + c0 + tx * 4) = make_float4(v0, v1, v2, v3);
        } else {
            ushort4 w;
            w.x = f2bf(v0); w.y = f2bf(v1); w.z = f2bf(v2); w.w = f2bf(v3);
            *(ushort4*)(Cb + (size_t)gm * TFw + (c0 - bstart) + tx * 4) = w;
        }
    }
}

// aggregate: ONE wave per node (FPL = TF/64 features per lane, bf16 gather). Emits agg as plain bf16.
template <int F>
__global__ __launch_bounds__(256) void aggregate(const float* __restrict__ ABa, const ushort_t* __restrict__ ABb,
                                                 const int* __restrict__ cnt, const int* __restrict__ csr_src,
                                                 const float2* __restrict__ csr_ea, const float* __restrict__ U,
                                                 ushort_t* __restrict__ agg_b, float2* __restrict__ sc) {
    const int TF = 2 * F;
    const int FPL = TF / 64;  // 1 (F=32) or 2 (F=64)
    int lane = threadIdx.x & 63;
    int n = blockIdx.x * 4 + (threadIdx.x >> 6);
    if (n >= NN) return;
    int f0 = FPL * lane;

    float base[FPL], u0[FPL], u1[FPL], sum[FPL], sq[FPL], mn[FPL], mx[FPL];
#pragma unroll
    for (int r = 0; r < FPL; ++r) {
        base[r] = ABa[(size_t)n * TF + f0 + r];
        u0[r] = U[f0 + r];
        u1[r] = U[TF + f0 + r];
        sum[r] = 0.f; sq[r] = 0.f; mn[r] = FLT_MAX; mx[r] = -FLT_MAX;
    }
    int deg = cnt[n];
    int ec = deg < CAP ? deg : CAP;
    if (ec > 0) {
        int ebase = n * CAP;
        int myi = lane < ec ? lane : ec - 1;
        int msrc = csr_src[ebase + myi];
        float2 mea = csr_ea[ebase + myi];
        for (int e = 0; e < ec; e += 8) {
            int sb[8]; float ex[8], ey[8];
            unsigned wv[8];
#pragma unroll
            for (int i = 0; i < 8; ++i) {
                sb[i] = __shfl(msrc, e + i);
                ex[i] = __shfl(mea.x, e + i);
                ey[i] = __shfl(mea.y, e + i);
            }
#pragma unroll
            for (int i = 0; i < 8; ++i) {
                if (e + i < ec) {
                    if (FPL == 2)
                        wv[i] = *(const unsigned*)(ABb + (size_t)sb[i] * TF + f0);
                    else
                        wv[i] = ABb[(size_t)sb[i] * TF + f0];
                }
            }
#pragma unroll
            for (int i = 0; i < 8; ++i) {
                if (e + i < ec) {
                    float v[FPL];
                    if (FPL == 2) {
                        v[0] = bitsf(wv[i] << 16);
                        v[1] = bitsf(wv[i] & 0xffff0000u);
                    } else {
                        v[0] = bitsf(wv[i] << 16);
                    }
#pragma unroll
                    for (int r = 0; r < FPL; ++r) {
                        float q = fmaf(ex[i], u0[r], fmaf(ey[i], u1[r], v[r]));
                        sum[r] += q;
                        sq[r] = fmaf(q, q, sq[r]);
                        mn[r] = fminf(mn[r], q);
                        mx[r] = fmaxf(mx[r], q);
                    }
                }
            }
        }
    }
    float d = (float)(deg > 1 ? deg : 1);
    float inv_d = 1.f / d;
    bool has = deg > 0;
#pragma unroll
    for (int r = 0; r < FPL; ++r) {
        float mean_q = sum[r] * inv_d;
        float var = sq[r] * inv_d - mean_q * mean_q;
        float stdv = sqrtf(fmaxf(var, 0.f) + 1e-5f);
        float mean = has ? base[r] + mean_q : 0.f;
        float vmn = has ? base[r] + mn[r] : 0.f;
        float vmx = has ? base[r] + mx[r] : 0.f;
        int f = f0 + r;
        int t = f / F, o = f - t * F;
        size_t rowb = (size_t)n * (4 * TF) + (size_t)t * (4 * F);
        agg_b[rowb + o] = f2bf(mean);
        agg_b[rowb + F + o] = f2bf(vmn);
        agg_b[rowb + 2 * F + o] = f2bf(vmx);
        agg_b[rowb + 3 * F + o] = f2bf(stdv);
    }
    if (lane == 0) {
        float logd = logf(d + 1.f);
        sc[n] = make_float2(logd / kAVG_LOG, kAVG_LOG / logd);
    }
}

// MFMA merged Z+final GEMM. A bf16 (single), B split hi/lo: Y = Ah@Bh + Ah@Bl.
// Block 64 rows x 192 cols; wave w owns col-frags {w, w+4, w+8} x 4 row-frags.
// Register-prefetch pipeline: k0+1 global loads issued before k0's MFMA block.
template <int F, bool POOL>
__global__ __launch_bounds__(256) void gemm_zf(
    const ushort_t* __restrict__ xs_b, const ushort_t* __restrict__ agg_b,
    const ushort_t* __restrict__ Bh, const ushort_t* __restrict__ Bl,
    const float* __restrict__ bias_zf, const float2* __restrict__ sc,
    float* __restrict__ H, ushort_t* __restrict__ H_b,
    const int* __restrict__ batch, float* __restrict__ pool) {
    const int KT = 9 * F;
    extern __shared__ char smem[];
    ushort_t* A_s  = (ushort_t*)smem;        // [64][40]
    ushort_t* Bh_s = A_s + 64 * 40;          // [192][40]
    ushort_t* Bl_s = Bh_s + 192 * 40;        // [192][40]
    float* hbuf = (float*)smem;              // POOL alias [64][68]

    int m0 = blockIdx.x * 64;
    int tid = threadIdx.x;
    int lane = tid & 63;
    int wave = tid >> 6;
    int ln = lane & 15, quad = lane >> 4;

    floatx4 acc[4][3];
#pragma unroll
    for (int i = 0; i < 4; ++i)
#pragma unroll
        for (int j = 0; j < 3; ++j) acc[i][j] = (floatx4)(0.f);

    int arow = tid >> 2, asg = tid & 3;
    int agm = m0 + arow;
    int bcol[3], bsg[3];
#pragma unroll
    for (int p = 0; p < 3; ++p) {
        int idx = tid + 256 * p;
        bcol[p] = idx >> 2;
        bsg[p] = idx & 3;
    }

    const short8 zero8 = {0, 0, 0, 0, 0, 0, 0, 0};
    short8 pa, pbh[3], pbl[3];
    // prefetch k0 = 0
    {
        int c0 = asg * 8;  // always < F at k0=0
        pa = zero8;
        if (agm < NN) pa = *(const short8*)(xs_b + (size_t)agm * F + c0);
#pragma unroll
        for (int p = 0; p < 3; ++p) {
            pbh[p] = *(const short8*)(Bh + (size_t)bcol[p] * KT + bsg[p] * 8);
            pbl[p] = *(const short8*)(Bl + (size_t)bcol[p] * KT + bsg[p] * 8);
        }
    }

    for (int k0 = 0; k0 < KT; k0 += 32) {
        // write staged regs -> LDS
        *(short8*)&A_s[arow * 40 + asg * 8] = pa;
#pragma unroll
        for (int p = 0; p < 3; ++p) {
            *(short8*)&Bh_s[bcol[p] * 40 + bsg[p] * 8] = pbh[p];
            *(short8*)&Bl_s[bcol[p] * 40 + bsg[p] * 8] = pbl[p];
        }
        __syncthreads();
        short8 ah[4], bh[3], bl[3];
#pragma unroll
        for (int rf = 0; rf < 4; ++rf)
            ah[rf] = *(short8*)&A_s[(rf * 16 + ln) * 40 + quad * 8];
#pragma unroll
        for (int b = 0; b < 3; ++b) {
            int col = b * 64 + wave * 16 + ln;
            bh[b] = *(short8*)&Bh_s[col * 40 + quad * 8];
            bl[b] = *(short8*)&Bl_s[col * 40 + quad * 8];
        }
        // issue next-k0 global loads (overlap with MFMA below)
        int kn = k0 + 32;
        if (kn < KT) {
            int c0 = kn + asg * 8;
            pa = zero8;
            if (agm < NN) {
                pa = (c0 < F) ? *(const short8*)(xs_b + (size_t)agm * F + c0)
                              : *(const short8*)(agg_b + (size_t)agm * 8 * F + (c0 - F));
            }
#pragma unroll
            for (int p = 0; p < 3; ++p) {
                pbh[p] = *(const short8*)(Bh + (size_t)bcol[p] * KT + kn + bsg[p] * 8);
                pbl[p] = *(const short8*)(Bl + (size_t)bcol[p] * KT + kn + bsg[p] * 8);
            }
        }
#pragma unroll
        for (int rf = 0; rf < 4; ++rf)
#pragma unroll
            for (int b = 0; b < 3; ++b) {
                acc[rf][b] = __builtin_amdgcn_mfma_f32_16x16x32_bf16(ah[rf], bh[b], acc[rf][b], 0, 0, 0);
                acc[rf][b] = __builtin_amdgcn_mfma_f32_16x16x32_bf16(ah[rf], bl[b], acc[rf][b], 0, 0, 0);
            }
        __syncthreads();
    }

    int ocol = wave * 16 + ln;  // output col 0..63
    float bcolv = bias_zf[ocol];

#pragma unroll
    for (int rf = 0; rf < 4; ++rf) {
#pragma unroll
        for (int reg = 0; reg < 4; ++reg) {
            int r = rf * 16 + quad * 4 + reg;
            int gm = m0 + r;
            float2 s = make_float2(0.f, 0.f);
            if (gm < NN) s = sc[gm];
            float y = acc[rf][0][reg] + s.x * acc[rf][1][reg] + s.y * acc[rf][2][reg] + bcolv;
            y = fmaxf(y, 0.f);
            if (POOL) {
                hbuf[r * 68 + ocol] = (gm < NN) ? y : 0.f;
            } else if (gm < NN) {
                H[(size_t)gm * 64 + ocol] = y;
                H_b[(size_t)gm * 64 + ocol] = f2bf(y);
            }
        }
    }
    if (POOL) {
        __syncthreads();
        int col = tid & 63, grp = tid >> 6;
        float a = 0.f;
        int cur = -1;
        for (int i = 0; i < 16; ++i) {
            int r = grp * 16 + i;
            int gm = m0 + r;
            if (gm >= NN) break;
            int b = batch[gm];
            if (b != cur) {
                if (cur >= 0) atomicAdd(&pool[cur * 64 + col], a);
                cur = b; a = 0.f;
            }
            a += hbuf[r * 68 + col];
        }
        if (cur >= 0) atomicAdd(&pool[cur * 64 + col], a);
    }
}

__global__ __launch_bounds__(256) void head_kernel(const float* __restrict__ gpool, const float* __restrict__ hls,
                                                   const float* __restrict__ W1, const float* __restrict__ b1,
                                                   const float* __restrict__ W2, const float* __restrict__ b2,
                                                   const float* __restrict__ W3, const float* __restrict__ b3,
                                                   float* __restrict__ out) {
    __shared__ float gin[64][96];
    __shared__ float r1[64][64];
    __shared__ float r2[64][64];
    int tid = threadIdx.x;
    for (int idx = tid; idx < 64 * 96; idx += 256) {
        int g = idx / 96, j = idx % 96;
        gin[g][j] = (j < 64) ? gpool[g * 64 + j] : hls[g * 32 + (j - 64)];
    }
    __syncthreads();
    for (int idx = tid; idx < 64 * 64; idx += 256) {
        int g = idx / 64, j = idx % 64;
        float acc = b1[j];
        for (int k = 0; k < 96; ++k) acc = fmaf(gin[g][k], W1[k * 64 + j], acc);
        r1[g][j] = fmaxf(acc, 0.f);
    }
    __syncthreads();
    for (int idx = tid; idx < 64 * 64; idx += 256) {
        int g = idx / 64, j = idx % 64;
        float acc = b2[j];
        for (int k = 0; k < 64; ++k) acc = fmaf(r1[g][k], W2[k * 64 + j], acc);
        r2[g][j] = fmaxf(acc, 0.f);
    }
    __syncthreads();
    if (tid < 64) {
        float acc = b3[0];
        for (int k = 0; k < 64; ++k) acc = fmaf(r2[tid][k], W3[k], acc);
        out[tid] = acc;
    }
}

extern "C" void kernel_launch(void* const* d_in, const int* in_sizes, int n_in,
                              void* d_out, int out_size, void* d_ws, size_t ws_size,
                              hipStream_t stream) {
    (void)in_sizes; (void)n_in; (void)out_size; (void)ws_size;
    const float* x     = (const float*)d_in[0];
    const float* eattr = (const float*)d_in[1];
    const float* hls   = (const float*)d_in[2];
    const int*   eidx  = (const int*)d_in[3];
    const int*   batch = (const int*)d_in[4];
    const float* We[2]    = {(const float*)d_in[5],  (const float*)d_in[13]};
    const float* be[2]    = {(const float*)d_in[6],  (const float*)d_in[14]};
    const float* Wpre[2]  = {(const float*)d_in[7],  (const float*)d_in[15]};
    const float* bpre[2]  = {(const float*)d_in[8],  (const float*)d_in[16]};
    const float* Wpost[2] = {(const float*)d_in[9],  (const float*)d_in[17]};
    const float* bpost[2] = {(const float*)d_in[10], (const float*)d_in[18]};
    const float* Wlin[2]  = {(const float*)d_in[11], (const float*)d_in[19]};
    const float* blin[2]  = {(const float*)d_in[12], (const float*)d_in[20]};
    const float* W1 = (const float*)d_in[21]; const float* b1 = (const float*)d_in[22];
    const float* W2 = (const float*)d_in[23]; const float* b2 = (const float*)d_in[24];
    const float* W3 = (const float*)d_in[25]; const float* b3 = (const float*)d_in[26];
    float* out = (float*)d_out;

    char* ws = (char*)d_ws;
    size_t off = 0;
    auto carve = [&](size_t bytes) -> char* {
        char* p = ws + off;
        off = (off + bytes + 255) & ~(size_t)255;
        return p;
    };
    int*      cnt     = (int*)carve((size_t)NN * 4);
    int*      csr_src = (int*)carve((size_t)NN * CAP * 4);
    float2*   csr_ea  = (float2*)carve((size_t)NN * CAP * 8);
    float*    ABa     = (float*)carve((size_t)NN * 128 * 4);      // fp32 dst-projection
    ushort_t* ABb     = (ushort_t*)carve((size_t)NN * 128 * 2);   // bf16 src-projection
    ushort_t* agg_b   = (ushort_t*)carve((size_t)NN * 512 * 2);   // bf16 agg
    float2*   sc      = (float2*)carve((size_t)NN * 8);
    ushort_t* xs_b    = (ushort_t*)carve((size_t)NN * 32 * 2);
    float*    h1      = (float*)carve((size_t)NN * 64 * 4);
    ushort_t* h1_b    = (ushort_t*)carve((size_t)NN * 64 * 2);
    float*    U       = (float*)carve(256 * 4);
    float*    Wab     = (float*)carve(16384 * 4);
    float*    bias_ab = (float*)carve(256 * 4);
    ushort_t* Bh      = (ushort_t*)carve((size_t)192 * 576 * 2);
    ushort_t* Bl      = (ushort_t*)carve((size_t)192 * 576 * 2);
    float*    bias_zf = (float*)carve(64 * 4);
    float*    pool    = (float*)carve(64 * 64 * 4);

    const int MB128 = (NN + 127) / 128;  // 391
    const int MB64  = (NN + 63) / 64;    // 782
    const int SMEM_ZF = (64 * 40 + 192 * 40 + 192 * 40) * 2;  // 35840 (>= POOL alias 17408)

    zero_init<<<(NN + 255) / 256, 256, 0, stream>>>(cnt, pool);
    build_csr<<<(EE + 255) / 256, 256, 0, stream>>>(eidx, eattr, cnt, csr_src, csr_ea);
    cast_x<<<(NN * 32 + 255) / 256, 256, 0, stream>>>(x, xs_b, NN * 32);

    // ---------------- layer 0 (F=32, TF=64, KT=288) ----------------
    prep_ab<32><<<1, 256, 0, stream>>>(We[0], be[0], Wpre[0], bpre[0], U, Wab, bias_ab);
    prep_zf<32><<<12, 256, 0, stream>>>(Wpost[0], Wlin[0], bpost[0], blin[0], Bh, Bl, bias_zf);
    gemm_bias<<<dim3(MB128, 2), 256, 0, stream>>>(x, Wab, bias_ab, ABa, ABb, NN, 32, 128, 64);
    aggregate<32><<<(NN + 3) / 4, 256, 0, stream>>>(ABa, ABb, cnt, csr_src, csr_ea, U, agg_b, sc);
    gemm_zf<32, false><<<MB64, 256, SMEM_ZF, stream>>>(xs_b, agg_b, Bh, Bl, bias_zf, sc,
                                                       h1, h1_b, batch, pool);

    // ---------------- layer 1 (F=64, TF=128, KT=576) ----------------
    prep_ab<64><<<1, 256, 0, stream>>>(We[1], be[1], Wpre[1], bpre[1], U, Wab, bias_ab);
    prep_zf<64><<<12, 256, 0, stream>>>(Wpost[1], Wlin[1], bpost[1], blin[1], Bh, Bl, bias_zf);
    gemm_bias<<<dim3(MB128, 4), 256, 0, stream>>>(h1, Wab, bias_ab, ABa, ABb, NN, 64, 256, 128);
    aggregate<64><<<(NN + 3) / 4, 256, 0, stream>>>(ABa, ABb, cnt, csr_src, csr_ea, U, agg_b, sc);
    gemm_zf<64, true><<<MB64, 256, SMEM_ZF, stream>>>(h1_b, agg_b, Bh, Bl, bias_zf, sc,
                                                      nullptr, nullptr, batch, pool);

    // ---------------- head ----------------
    head_kernel<<<1, 256, 0, stream>>>(pool, hls, W1, b1, W2, b2, W3, b3, out);
}